// Round 14
// baseline (2087.234 us; speedup 1.0000x reference)
//
#include <hip/hip_runtime.h>
#include <math.h>

#define DC 256
#define NBINS 1024
#define NQ 8
#define NTOK 32768      // B*T
#define D_IN 512
#define DCH 32
#define TOK 64          // tokens per stage-block -> 512 blocks/stage
#define STG_BLOCKS (NTOK / TOK)
#define STG_THREADS 512 // 8 waves: bins split 8-way, 2 waves/SIMD
#define MARGIN 5e-3f    // fast(MFMA) top-2 gap below which we re-rank with np bits

typedef __attribute__((ext_vector_type(8))) short short8v;   // 8 bf16 (4 VGPR)
typedef __attribute__((ext_vector_type(4))) float f32x4;

// ---- bf16 helpers (RNE, matches hw cvt) ----
__device__ __forceinline__ unsigned short f2bf(float x) {
  unsigned u = __float_as_uint(x);
  return (unsigned short)((u + 0x7fffu + ((u >> 16) & 1u)) >> 16);
}
__device__ __forceinline__ float bf2f(unsigned short h) {
  return __uint_as_float(((unsigned)h) << 16);
}
__device__ __forceinline__ void store8s(unsigned short* dst, const unsigned short* v) {
  uint4 u;
  u.x = v[0] | ((unsigned)v[1] << 16); u.y = v[2] | ((unsigned)v[3] << 16);
  u.z = v[4] | ((unsigned)v[5] << 16); u.w = v[6] | ((unsigned)v[7] << 16);
  *reinterpret_cast<uint4*>(dst) = u;
}
__device__ __forceinline__ short8v load8s(const unsigned short* p) {
  return __builtin_bit_cast(short8v, *reinterpret_cast<const float4*>(p));
}

// ---- numpy pairwise_sum bit-emulation (8 accumulators, 128-block) ----
__device__ __forceinline__ float np_sumsq128(const float* a) {
#pragma clang fp contract(off)
  float r0 = a[0] * a[0], r1 = a[1] * a[1], r2 = a[2] * a[2], r3 = a[3] * a[3];
  float r4 = a[4] * a[4], r5 = a[5] * a[5], r6 = a[6] * a[6], r7 = a[7] * a[7];
  for (int i = 8; i < 128; i += 8) {
    r0 += a[i + 0] * a[i + 0]; r1 += a[i + 1] * a[i + 1];
    r2 += a[i + 2] * a[i + 2]; r3 += a[i + 3] * a[i + 3];
    r4 += a[i + 4] * a[i + 4]; r5 += a[i + 5] * a[i + 5];
    r6 += a[i + 6] * a[i + 6]; r7 += a[i + 7] * a[i + 7];
  }
  return ((r0 + r1) + (r2 + r3)) + ((r4 + r5) + (r6 + r7));
}
__device__ __forceinline__ float np_sumsq256(const float* a) {
#pragma clang fp contract(off)
  float lo = np_sumsq128(a);
  float hi = np_sumsq128(a + 128);
  return lo + hi;
}

// ---------------- K0: codebook squared norms, np-pairwise bits ----------------
__global__ void e2_np_kernel(const float* __restrict__ cb, float* __restrict__ e2) {
  int b = blockIdx.x * 256 + threadIdx.x;
  e2[b] = np_sumsq256(cb + (size_t)b * DC);
}

// ---------------- K0b: codebook bf16 hi/lo pre-split ----------------
// layout: [s][k8 0..31][bin 0..1023][8] bf16
__global__ void presplit_kernel(const float* __restrict__ cb,
                                unsigned short* __restrict__ cb_h,
                                unsigned short* __restrict__ cb_l) {
  int id = blockIdx.x * 256 + threadIdx.x;   // (s*32+k8)*1024 + bin
  int sk = id >> 10, bin = id & 1023;
  int s = sk >> 5, k8 = sk & 31;
  const float* src = cb + ((size_t)s * NBINS + bin) * DC + k8 * 8;
  unsigned short hh[8], ll[8];
#pragma unroll
  for (int j = 0; j < 8; ++j) {
    float x = src[j];
    unsigned short h = f2bf(x);
    hh[j] = h;
    ll[j] = f2bf(x - bf2f(h));
  }
  store8s(cb_h + (size_t)id * 8, hh);
  store8s(cb_l + (size_t)id * 8, ll);
}

// ---------------- K1: in-projection, OpenBLAS-sgemm bit-emulation ----------------
__global__ __launch_bounds__(256) void in_proj_kernel(
    const float* __restrict__ x, const float* __restrict__ in_w,
    const float* __restrict__ in_b, float* __restrict__ res) {
  __shared__ __align__(16) float aT[DCH][68];
  __shared__ __align__(16) float bT[DCH][68];
  const int thr = threadIdx.x;
  const int tx = thr & 15, ty = thr >> 4;
  const int m0 = blockIdx.x * 64, n0 = blockIdx.y * 64;
  float acc[4][4] = {};
  float s1[4][4] = {};
  for (int kc = 0; kc < D_IN; kc += DCH) {
    if (kc == 384) {
#pragma unroll
      for (int i = 0; i < 4; ++i)
#pragma unroll
        for (int j = 0; j < 4; ++j) { s1[i][j] = acc[i][j]; acc[i][j] = 0.f; }
    }
    __syncthreads();
#pragma unroll
    for (int i = 0; i < 2; ++i) {
      int q = thr + 256 * i;
      int m = q >> 3, kk = (q & 7) << 2;
      float4 v = *reinterpret_cast<const float4*>(x + (size_t)(m0 + m) * D_IN + kc + kk);
      aT[kk + 0][m] = v.x; aT[kk + 1][m] = v.y; aT[kk + 2][m] = v.z; aT[kk + 3][m] = v.w;
      float4 w = *reinterpret_cast<const float4*>(in_w + (size_t)(n0 + m) * D_IN + kc + kk);
      bT[kk + 0][m] = w.x; bT[kk + 1][m] = w.y; bT[kk + 2][m] = w.z; bT[kk + 3][m] = w.w;
    }
    __syncthreads();
#pragma unroll 8
    for (int d = 0; d < DCH; ++d) {
      float4 a = *reinterpret_cast<const float4*>(&aT[d][ty * 4]);
      float4 b = *reinterpret_cast<const float4*>(&bT[d][tx * 4]);
      float av[4] = {a.x, a.y, a.z, a.w};
      float bv[4] = {b.x, b.y, b.z, b.w};
#pragma unroll
      for (int i = 0; i < 4; ++i)
#pragma unroll
        for (int j = 0; j < 4; ++j) acc[i][j] = fmaf(av[i], bv[j], acc[i][j]);
    }
  }
#pragma unroll
  for (int i = 0; i < 4; ++i) {
    int m = m0 + ty * 4 + i, n = n0 + tx * 4;
    float4 hv;
#pragma unroll
    for (int j = 0; j < 4; ++j) {
#pragma clang fp contract(off)
      float c = s1[i][j] + acc[i][j];
      float pre = c + in_b[n + j];
      ((float*)&hv)[j] = tanhf(pre);
    }
    *reinterpret_cast<float4*>(res + (size_t)m * DC + n) = hv;
  }
}

// ---------------- K2: per-stage RVQ — 8-wave MFMA score + prefetch + np re-rank ----------------
// TOK=64, 512 threads: 8 waves split the 1024 bins (128/wave, 2 chunks of 64).
// A(-2r hi/lo) in LDS (64KB); B direct from L2/L3 with 1-deep register
// ping-pong prefetch across ksteps; pass-major MFMA; per-wave LDS top-2.
__global__ __launch_bounds__(STG_THREADS, 2) void stage_kernel(
    const float* __restrict__ cb, const float* __restrict__ e2,
    const unsigned short* __restrict__ cb_h, const unsigned short* __restrict__ cb_l,
    float* __restrict__ res, float* __restrict__ idx_f, double* __restrict__ partial,
    int s) {
  __shared__ __align__(16) unsigned short a_hi[32 * TOK * 8];  // 32KB
  __shared__ __align__(16) unsigned short a_lo[32 * TOK * 8];  // 32KB
  __shared__ float m1s[8 * TOK], m2s[8 * TOK];
  __shared__ int   i1s[8 * TOK];
  __shared__ int   win_l[TOK], flag_l[TOK];
  __shared__ __align__(16) float rrow_s[256];
  __shared__ float redf[8];
  __shared__ int   redi[8];
  __shared__ double wsum[8];

  const int thr = threadIdx.x;
  const int lane = thr & 63;
  const int w = thr >> 6;        // wave 0..7 -> bins [w*128, w*128+128)
  const int lg = lane >> 4;      // k-subgroup (A/B), row-subgroup (C)
  const int lc = lane & 15;      // A row-in-tile / B,C col(bin)-in-tile
  const int m0 = blockIdx.x * TOK;
  const float* cbs = cb + (size_t)s * NBINS * DC;
  const float* e2s = e2 + (size_t)s * NBINS;
  const unsigned short* bhp = cb_h + (size_t)s * (32 * 1024 * 8);
  const unsigned short* blp = cb_l + (size_t)s * (32 * 1024 * 8);
  double sqacc = 0.0;

  // ---- A build: -2*r as bf16 hi/lo into LDS (8 threads/row, 32 d each) ----
  {
    int row = thr >> 3, d0 = (thr & 7) << 5;
    const float* rrow = res + (size_t)(m0 + row) * DC + d0;
#pragma unroll
    for (int c = 0; c < 4; ++c) {
      float4 r0 = *reinterpret_cast<const float4*>(rrow + c * 8);
      float4 r1 = *reinterpret_cast<const float4*>(rrow + c * 8 + 4);
      float rv[8] = {r0.x, r0.y, r0.z, r0.w, r1.x, r1.y, r1.z, r1.w};
      unsigned short hh[8], ll[8];
#pragma unroll
      for (int j = 0; j < 8; ++j) {
        float xv = -2.0f * rv[j];
        unsigned short h = f2bf(xv);
        hh[j] = h; ll[j] = f2bf(xv - bf2f(h));
      }
      int k8 = (d0 >> 3) + c;
      store8s(a_hi + ((size_t)k8 * TOK + row) * 8, hh);
      store8s(a_lo + ((size_t)k8 * TOK + row) * 8, ll);
    }
  }
  m1s[thr] = 3.4028235e38f; m2s[thr] = 3.4028235e38f; i1s[thr] = 0;
  __syncthreads();

  // ---- MFMA scoring: dist = e2 - 2*r.e, 3-pass hi/lo, pass-major, prefetch ----
  for (int c = 0; c < 2; ++c) {
    const int bbase = w * 128 + c * 64;
    f32x4 acc[4][4];
#pragma unroll
    for (int nt = 0; nt < 4; ++nt) {
      float ev = e2s[bbase + nt * 16 + lc];
      f32x4 iv = {ev, ev, ev, ev};
#pragma unroll
      for (int rt = 0; rt < 4; ++rt) acc[rt][nt] = iv;
    }
    short8v b0h[4], b0l[4], b1h[4], b1l[4];
#pragma unroll
    for (int nt = 0; nt < 4; ++nt) {   // kstep 0 -> b0
      size_t boff = ((size_t)lg * 1024 + bbase + nt * 16 + lc) * 8;
      b0h[nt] = load8s(bhp + boff);
      b0l[nt] = load8s(blp + boff);
    }
#pragma unroll
    for (int kp = 0; kp < 8; kp += 2) {
      // prefetch kstep kp+1 -> b1
#pragma unroll
      for (int nt = 0; nt < 4; ++nt) {
        size_t boff = ((size_t)((kp + 1) * 4 + lg) * 1024 + bbase + nt * 16 + lc) * 8;
        b1h[nt] = load8s(bhp + boff);
        b1l[nt] = load8s(blp + boff);
      }
      // A frags kp + pass-major MFMA on b0
      {
        short8v ah[4], al[4];
#pragma unroll
        for (int rt = 0; rt < 4; ++rt) {
          int off = ((kp * 4 + lg) * TOK + rt * 16 + lc) * 8;
          ah[rt] = load8s(a_hi + off);
          al[rt] = load8s(a_lo + off);
        }
#pragma unroll
        for (int nt = 0; nt < 4; ++nt)
#pragma unroll
          for (int rt = 0; rt < 4; ++rt)
            acc[rt][nt] = __builtin_amdgcn_mfma_f32_16x16x32_bf16(ah[rt], b0h[nt], acc[rt][nt], 0, 0, 0);
#pragma unroll
        for (int nt = 0; nt < 4; ++nt)
#pragma unroll
          for (int rt = 0; rt < 4; ++rt)
            acc[rt][nt] = __builtin_amdgcn_mfma_f32_16x16x32_bf16(ah[rt], b0l[nt], acc[rt][nt], 0, 0, 0);
#pragma unroll
        for (int nt = 0; nt < 4; ++nt)
#pragma unroll
          for (int rt = 0; rt < 4; ++rt)
            acc[rt][nt] = __builtin_amdgcn_mfma_f32_16x16x32_bf16(al[rt], b0h[nt], acc[rt][nt], 0, 0, 0);
      }
      // prefetch kstep kp+2 -> b0
      if (kp + 2 < 8) {
#pragma unroll
        for (int nt = 0; nt < 4; ++nt) {
          size_t boff = ((size_t)((kp + 2) * 4 + lg) * 1024 + bbase + nt * 16 + lc) * 8;
          b0h[nt] = load8s(bhp + boff);
          b0l[nt] = load8s(blp + boff);
        }
      }
      // A frags kp+1 + pass-major MFMA on b1
      {
        short8v ah[4], al[4];
#pragma unroll
        for (int rt = 0; rt < 4; ++rt) {
          int off = (((kp + 1) * 4 + lg) * TOK + rt * 16 + lc) * 8;
          ah[rt] = load8s(a_hi + off);
          al[rt] = load8s(a_lo + off);
        }
#pragma unroll
        for (int nt = 0; nt < 4; ++nt)
#pragma unroll
          for (int rt = 0; rt < 4; ++rt)
            acc[rt][nt] = __builtin_amdgcn_mfma_f32_16x16x32_bf16(ah[rt], b1h[nt], acc[rt][nt], 0, 0, 0);
#pragma unroll
        for (int nt = 0; nt < 4; ++nt)
#pragma unroll
          for (int rt = 0; rt < 4; ++rt)
            acc[rt][nt] = __builtin_amdgcn_mfma_f32_16x16x32_bf16(ah[rt], b1l[nt], acc[rt][nt], 0, 0, 0);
#pragma unroll
        for (int nt = 0; nt < 4; ++nt)
#pragma unroll
          for (int rt = 0; rt < 4; ++rt)
            acc[rt][nt] = __builtin_amdgcn_mfma_f32_16x16x32_bf16(al[rt], b1h[nt], acc[rt][nt], 0, 0, 0);
      }
    }
    // fold this chunk into per-wave LDS top-2 (bins ascending)
#pragma unroll
    for (int rt = 0; rt < 4; ++rt)
#pragma unroll
      for (int reg = 0; reg < 4; ++reg) {
        float m1 = 3.4028235e38f, m2 = 3.4028235e38f; int i1 = 0;
#pragma unroll
        for (int nt = 0; nt < 4; ++nt) {
          float v = acc[rt][nt][reg];
          int b = bbase + nt * 16 + lc;
          if (v < m1) { m2 = m1; m1 = v; i1 = b; }
          else m2 = fminf(m2, v);
        }
#pragma unroll
        for (int msk = 1; msk < 16; msk <<= 1) {
          float om1 = __shfl_xor(m1, msk, 64);
          float om2 = __shfl_xor(m2, msk, 64);
          int   oi1 = __shfl_xor(i1, msk, 64);
          if (om1 < m1 || (om1 == m1 && oi1 < i1)) { m2 = fminf(m1, om2); m1 = om1; i1 = oi1; }
          else m2 = fminf(m2, om1);
        }
        if (lc == 0) {
          int row = rt * 16 + lg * 4 + reg;
          int sidx = w * TOK + row;
          float pm1 = m1s[sidx], pm2 = m2s[sidx]; int pi1 = i1s[sidx];
          if (m1 < pm1 || (m1 == pm1 && i1 < pi1)) {
            m1s[sidx] = m1; m2s[sidx] = fminf(pm1, m2); i1s[sidx] = i1;
          } else {
            m2s[sidx] = fminf(pm2, m1);
          }
        }
      }
  }
  __syncthreads();
  // final per-row merge across the 8 waves -> winner + margin flag
  if (thr < TOK) {
    float m1 = m1s[thr], m2 = m2s[thr]; int i1 = i1s[thr];
#pragma unroll
    for (int ww = 1; ww < 8; ++ww) {
      float om1 = m1s[ww * TOK + thr], om2 = m2s[ww * TOK + thr];
      int oi1 = i1s[ww * TOK + thr];
      if (om1 < m1 || (om1 == m1 && oi1 < i1)) { m2 = fminf(m1, om2); m1 = om1; i1 = oi1; }
      else m2 = fminf(m2, om1);
    }
    win_l[thr] = i1;
    flag_l[thr] = (m2 - m1 < MARGIN) ? 1 : 0;
  }
  __syncthreads();
  // ---- np-bit re-rank for flagged rows (rare; uniform branch) ----
  for (int row = 0; row < TOK; ++row) {
    if (!flag_l[row]) continue;
    if (thr < 64)
      reinterpret_cast<float4*>(rrow_s)[thr] =
          reinterpret_cast<const float4*>(res + (size_t)(m0 + row) * DC)[thr];
    __syncthreads();
    float r2 = np_sumsq256(rrow_s);
    float best = 3.4028235e38f; int bb = 0;
#pragma unroll
    for (int jj = 0; jj < 2; ++jj) {
      int b = thr * 2 + jj;
      const float4* e4 = reinterpret_cast<const float4*>(cbs + (size_t)b * DC);
      const float4* r4 = reinterpret_cast<const float4*>(rrow_s);
      float accv = 0.f;
      for (int q = 0; q < 64; ++q) {   // d ascending: sgemm-chain bits
        float4 ev = e4[q], rv = r4[q];
        accv = fmaf(rv.x, ev.x, accv);
        accv = fmaf(rv.y, ev.y, accv);
        accv = fmaf(rv.z, ev.z, accv);
        accv = fmaf(rv.w, ev.w, accv);
      }
      {
#pragma clang fp contract(off)
        float t = r2 - 2.0f * accv;
        float dist = t + e2s[b];
        if (dist < best) { best = dist; bb = b; }
      }
    }
#pragma unroll
    for (int msk = 1; msk < 64; msk <<= 1) {
      float ov = __shfl_xor(best, msk, 64);
      int   ob = __shfl_xor(bb, msk, 64);
      if (ov < best || (ov == best && ob < bb)) { best = ov; bb = ob; }
    }
    if (lane == 0) { redf[w] = best; redi[w] = bb; }
    __syncthreads();
    if (thr == 0) {
      float bs = redf[0]; int bfin = redi[0];
#pragma unroll
      for (int ww = 1; ww < 8; ++ww)
        if (redf[ww] < bs || (redf[ww] == bs && redi[ww] < bfin)) { bs = redf[ww]; bfin = redi[ww]; }
      win_l[row] = bfin;
    }
    __syncthreads();
  }
  // ---- residual update (np state bits) + commit acc ----
  {
    int row = thr >> 3, d0 = (thr & 7) << 5;
    int wbin = win_l[row];
    const float* erow = cbs + (size_t)wbin * DC + d0;
    float* rrow = res + (size_t)(m0 + row) * DC + d0;
#pragma unroll
    for (int c = 0; c < 4; ++c) {
      float4 r0 = *reinterpret_cast<const float4*>(rrow + c * 8);
      float4 r1 = *reinterpret_cast<const float4*>(rrow + c * 8 + 4);
      float4 e0 = *reinterpret_cast<const float4*>(erow + c * 8);
      float4 e1 = *reinterpret_cast<const float4*>(erow + c * 8 + 4);
      float nv[8] = {r0.x - e0.x, r0.y - e0.y, r0.z - e0.z, r0.w - e0.w,
                     r1.x - e1.x, r1.y - e1.y, r1.z - e1.z, r1.w - e1.w};
#pragma unroll
      for (int j = 0; j < 8; ++j) sqacc += (double)nv[j] * nv[j];
      *reinterpret_cast<float4*>(rrow + c * 8) = (float4){nv[0], nv[1], nv[2], nv[3]};
      *reinterpret_cast<float4*>(rrow + c * 8 + 4) = (float4){nv[4], nv[5], nv[6], nv[7]};
    }
    if (thr < TOK) idx_f[(size_t)s * NTOK + m0 + thr] = (float)win_l[thr];
  }
  // deterministic per-block commit partial (fp64)
#pragma unroll
  for (int msk = 1; msk < 64; msk <<= 1) sqacc += __shfl_xor(sqacc, msk, 64);
  if (lane == 0) wsum[w] = sqacc;
  __syncthreads();
  if (thr == 0) {
    double t = 0.0;
#pragma unroll
    for (int ww = 0; ww < 8; ++ww) t += wsum[ww];
    partial[(size_t)s * STG_BLOCKS + blockIdx.x] = t;
  }
}

// ---------------- K4: finalize commit loss (fixed order, 8*512 partials) ----------------
__global__ void finalize_kernel(const double* __restrict__ partial, float* __restrict__ out_last) {
  __shared__ double acc_s[64];
  int t = threadIdx.x;
  double a = 0.0;
  for (int i = 0; i < 64; ++i) a += partial[(size_t)t * 64 + i];
  acc_s[t] = a;
  __syncthreads();
  if (t == 0) {
    double tot = 0.0;
    for (int i = 0; i < 64; ++i) tot += acc_s[i];
    out_last[0] = (float)(0.1 * tot / 8388608.0);
  }
}

// ---------------- K3: out-projection GEMM from gathered quantized ----------------
__global__ __launch_bounds__(256) void out_proj_kernel(
    const float* __restrict__ cb, const float* __restrict__ idx_f,
    const float* __restrict__ out_w, const float* __restrict__ out_b,
    float* __restrict__ out) {
  __shared__ __align__(16) float aT[DCH][68];
  __shared__ __align__(16) float bT[DCH][68];
  __shared__ int idx_l[NQ][64];
  const int thr = threadIdx.x;
  const int tx = thr & 15, ty = thr >> 4;
  const int m0 = blockIdx.x * 64, n0 = blockIdx.y * 64;
#pragma unroll
  for (int i = 0; i < 2; ++i) {
    int q = thr + 256 * i;
    int s = q >> 6, m = q & 63;
    idx_l[s][m] = (int)idx_f[(size_t)s * NTOK + m0 + m];
  }
  float acc[4][4] = {};
  for (int kc = 0; kc < DC; kc += DCH) {
    __syncthreads();
#pragma unroll
    for (int i = 0; i < 2; ++i) {
      int q = thr + 256 * i;
      int m = q >> 3, kk = (q & 7) << 2;
      float4 v = {0.f, 0.f, 0.f, 0.f};
#pragma unroll
      for (int s = 0; s < NQ; ++s) {
        const float4 e = *reinterpret_cast<const float4*>(
            cb + ((size_t)s * NBINS + idx_l[s][m]) * DC + kc + kk);
        v.x += e.x; v.y += e.y; v.z += e.z; v.w += e.w;
      }
      aT[kk + 0][m] = v.x; aT[kk + 1][m] = v.y; aT[kk + 2][m] = v.z; aT[kk + 3][m] = v.w;
      float4 wv = *reinterpret_cast<const float4*>(out_w + (size_t)(n0 + m) * DC + kc + kk);
      bT[kk + 0][m] = wv.x; bT[kk + 1][m] = wv.y; bT[kk + 2][m] = wv.z; bT[kk + 3][m] = wv.w;
    }
    __syncthreads();
#pragma unroll 8
    for (int d = 0; d < DCH; ++d) {
      float4 a = *reinterpret_cast<const float4*>(&aT[d][ty * 4]);
      float4 b = *reinterpret_cast<const float4*>(&bT[d][tx * 4]);
      float av[4] = {a.x, a.y, a.z, a.w};
      float bv[4] = {b.x, b.y, b.z, b.w};
#pragma unroll
      for (int i = 0; i < 4; ++i)
#pragma unroll
        for (int j = 0; j < 4; ++j) acc[i][j] = fmaf(av[i], bv[j], acc[i][j]);
    }
  }
#pragma unroll
  for (int i = 0; i < 4; ++i) {
    int m = m0 + ty * 4 + i, n = n0 + tx * 4;
    float4 o;
    o.x = acc[i][0] + out_b[n + 0];
    o.y = acc[i][1] + out_b[n + 1];
    o.z = acc[i][2] + out_b[n + 2];
    o.w = acc[i][3] + out_b[n + 3];
    *reinterpret_cast<float4*>(out + (size_t)m * D_IN + n) = o;
  }
}

extern "C" void kernel_launch(void* const* d_in, const int* in_sizes, int n_in,
                              void* d_out, int out_size, void* d_ws, size_t ws_size,
                              hipStream_t stream) {
  (void)in_sizes; (void)n_in; (void)out_size; (void)d_ws; (void)ws_size;
  const float* x     = (const float*)d_in[0];
  const float* in_w  = (const float*)d_in[1];
  const float* in_b  = (const float*)d_in[2];
  const float* out_w = (const float*)d_in[3];
  const float* out_b = (const float*)d_in[4];
  const float* cb    = (const float*)d_in[5];
  float* out = (float*)d_out;
  // d_out scratch layout (consumed before out_proj overwrites [0,16.7M)):
  float* res    = out;                                  // 8,388,608 f32 residual
  float* e2     = out + 8388608;                        // 8192 f32 (np bits)
  double* part  = (double*)(out + 8404992);             // 4096 f64 (8 stages x 512 blocks)
  unsigned short* cb_h = (unsigned short*)(out + 9000000);   // 2,097,152 bf16 (4MB)
  unsigned short* cb_l = (unsigned short*)(out + 10500000);  // 4MB
  float* idx_f  = out + 16777216;                       // 262,144 f32
  float* c_out  = out + 17039360;                       // 1 f32

  hipLaunchKernelGGL(e2_np_kernel, dim3(32), dim3(256), 0, stream, cb, e2);
  hipLaunchKernelGGL(presplit_kernel, dim3(1024), dim3(256), 0, stream, cb, cb_h, cb_l);
  hipLaunchKernelGGL(in_proj_kernel, dim3(512, 4), dim3(256), 0, stream, x, in_w, in_b, res);
  for (int s = 0; s < NQ; ++s) {
    hipLaunchKernelGGL(stage_kernel, dim3(STG_BLOCKS), dim3(STG_THREADS), 0, stream,
                       cb, e2, cb_h, cb_l, res, idx_f, part, s);
  }
  hipLaunchKernelGGL(finalize_kernel, dim3(1), dim3(64), 0, stream, part, c_out);
  hipLaunchKernelGGL(out_proj_kernel, dim3(512, 8), dim3(256), 0, stream, cb, idx_f, out_w, out_b, out);
}

// Round 15
// 1561.526 us; speedup vs baseline: 1.3367x; 1.3367x over previous
//
#include <hip/hip_runtime.h>
#include <math.h>

#define DC 256
#define NBINS 1024
#define NQ 8
#define NTOK 32768      // B*T
#define D_IN 512
#define DCH 32
#define TOK 64          // tokens per stage-block -> 512 blocks/stage
#define STG_BLOCKS (NTOK / TOK)
#define MARGIN 5e-3f    // fast(MFMA) top-2 gap below which we re-rank with np bits

typedef __attribute__((ext_vector_type(8))) short short8v;   // 8 bf16 (4 VGPR)
typedef __attribute__((ext_vector_type(4))) float f32x4;

// ---- bf16 helpers (RNE, matches hw cvt) ----
__device__ __forceinline__ unsigned short f2bf(float x) {
  unsigned u = __float_as_uint(x);
  return (unsigned short)((u + 0x7fffu + ((u >> 16) & 1u)) >> 16);
}
__device__ __forceinline__ float bf2f(unsigned short h) {
  return __uint_as_float(((unsigned)h) << 16);
}
__device__ __forceinline__ void store8s(unsigned short* dst, const unsigned short* v) {
  uint4 u;
  u.x = v[0] | ((unsigned)v[1] << 16); u.y = v[2] | ((unsigned)v[3] << 16);
  u.z = v[4] | ((unsigned)v[5] << 16); u.w = v[6] | ((unsigned)v[7] << 16);
  *reinterpret_cast<uint4*>(dst) = u;
}
__device__ __forceinline__ short8v load8s(const unsigned short* p) {
  return __builtin_bit_cast(short8v, *reinterpret_cast<const float4*>(p));
}

// ---- numpy pairwise_sum bit-emulation (8 accumulators, 128-block) ----
__device__ __forceinline__ float np_sumsq128(const float* a) {
#pragma clang fp contract(off)
  float r0 = a[0] * a[0], r1 = a[1] * a[1], r2 = a[2] * a[2], r3 = a[3] * a[3];
  float r4 = a[4] * a[4], r5 = a[5] * a[5], r6 = a[6] * a[6], r7 = a[7] * a[7];
  for (int i = 8; i < 128; i += 8) {
    r0 += a[i + 0] * a[i + 0]; r1 += a[i + 1] * a[i + 1];
    r2 += a[i + 2] * a[i + 2]; r3 += a[i + 3] * a[i + 3];
    r4 += a[i + 4] * a[i + 4]; r5 += a[i + 5] * a[i + 5];
    r6 += a[i + 6] * a[i + 6]; r7 += a[i + 7] * a[i + 7];
  }
  return ((r0 + r1) + (r2 + r3)) + ((r4 + r5) + (r6 + r7));
}
__device__ __forceinline__ float np_sumsq256(const float* a) {
#pragma clang fp contract(off)
  float lo = np_sumsq128(a);
  float hi = np_sumsq128(a + 128);
  return lo + hi;
}

// ---------------- K0: codebook squared norms, np-pairwise bits ----------------
__global__ void e2_np_kernel(const float* __restrict__ cb, float* __restrict__ e2) {
  int b = blockIdx.x * 256 + threadIdx.x;
  e2[b] = np_sumsq256(cb + (size_t)b * DC);
}

// ---------------- K0b: codebook bf16 hi/lo pre-split ----------------
// layout: [s][k8 0..31][bin 0..1023][8] bf16
__global__ void presplit_kernel(const float* __restrict__ cb,
                                unsigned short* __restrict__ cb_h,
                                unsigned short* __restrict__ cb_l) {
  int id = blockIdx.x * 256 + threadIdx.x;   // (s*32+k8)*1024 + bin
  int sk = id >> 10, bin = id & 1023;
  int s = sk >> 5, k8 = sk & 31;
  const float* src = cb + ((size_t)s * NBINS + bin) * DC + k8 * 8;
  unsigned short hh[8], ll[8];
#pragma unroll
  for (int j = 0; j < 8; ++j) {
    float x = src[j];
    unsigned short h = f2bf(x);
    hh[j] = h;
    ll[j] = f2bf(x - bf2f(h));
  }
  store8s(cb_h + (size_t)id * 8, hh);
  store8s(cb_l + (size_t)id * 8, ll);
}

// ---------------- K1: in-projection, OpenBLAS-sgemm bit-emulation ----------------
__global__ __launch_bounds__(256) void in_proj_kernel(
    const float* __restrict__ x, const float* __restrict__ in_w,
    const float* __restrict__ in_b, float* __restrict__ res) {
  __shared__ __align__(16) float aT[DCH][68];
  __shared__ __align__(16) float bT[DCH][68];
  const int thr = threadIdx.x;
  const int tx = thr & 15, ty = thr >> 4;
  const int m0 = blockIdx.x * 64, n0 = blockIdx.y * 64;
  float acc[4][4] = {};
  float s1[4][4] = {};
  for (int kc = 0; kc < D_IN; kc += DCH) {
    if (kc == 384) {
#pragma unroll
      for (int i = 0; i < 4; ++i)
#pragma unroll
        for (int j = 0; j < 4; ++j) { s1[i][j] = acc[i][j]; acc[i][j] = 0.f; }
    }
    __syncthreads();
#pragma unroll
    for (int i = 0; i < 2; ++i) {
      int q = thr + 256 * i;
      int m = q >> 3, kk = (q & 7) << 2;
      float4 v = *reinterpret_cast<const float4*>(x + (size_t)(m0 + m) * D_IN + kc + kk);
      aT[kk + 0][m] = v.x; aT[kk + 1][m] = v.y; aT[kk + 2][m] = v.z; aT[kk + 3][m] = v.w;
      float4 w = *reinterpret_cast<const float4*>(in_w + (size_t)(n0 + m) * D_IN + kc + kk);
      bT[kk + 0][m] = w.x; bT[kk + 1][m] = w.y; bT[kk + 2][m] = w.z; bT[kk + 3][m] = w.w;
    }
    __syncthreads();
#pragma unroll 8
    for (int d = 0; d < DCH; ++d) {
      float4 a = *reinterpret_cast<const float4*>(&aT[d][ty * 4]);
      float4 b = *reinterpret_cast<const float4*>(&bT[d][tx * 4]);
      float av[4] = {a.x, a.y, a.z, a.w};
      float bv[4] = {b.x, b.y, b.z, b.w};
#pragma unroll
      for (int i = 0; i < 4; ++i)
#pragma unroll
        for (int j = 0; j < 4; ++j) acc[i][j] = fmaf(av[i], bv[j], acc[i][j]);
    }
  }
#pragma unroll
  for (int i = 0; i < 4; ++i) {
    int m = m0 + ty * 4 + i, n = n0 + tx * 4;
    float4 hv;
#pragma unroll
    for (int j = 0; j < 4; ++j) {
#pragma clang fp contract(off)
      float c = s1[i][j] + acc[i][j];
      float pre = c + in_b[n + j];
      ((float*)&hv)[j] = tanhf(pre);
    }
    *reinterpret_cast<float4*>(res + (size_t)m * DC + n) = hv;
  }
}

// ---------------- K2a: per-stage MFMA scoring (ablation split: score only) ----------------
// R12's exact score machinery: A(-2r hi/lo) in LDS, 3-pass hi/lo MFMA pass-major,
// per-wave LDS top-2 fold, cross-wave merge -> win/flag to global scratch.
__global__ __launch_bounds__(256, 2) void score_kernel(
    const float* __restrict__ e2,
    const unsigned short* __restrict__ cb_h, const unsigned short* __restrict__ cb_l,
    const float* __restrict__ res, int* __restrict__ win_g, int* __restrict__ flag_g,
    int s) {
  __shared__ __align__(16) unsigned short a_hi[32 * TOK * 8];  // 32KB
  __shared__ __align__(16) unsigned short a_lo[32 * TOK * 8];  // 32KB
  __shared__ float m1s[4 * TOK], m2s[4 * TOK];
  __shared__ int   i1s[4 * TOK];

  const int thr = threadIdx.x;
  const int lane = thr & 63;
  const int w = thr >> 6;        // wave 0..3 -> bins [w*256, w*256+256)
  const int lg = lane >> 4;      // k-subgroup (A/B), row-subgroup (C)
  const int lc = lane & 15;      // A row-in-tile / B,C col(bin)-in-tile
  const int m0 = blockIdx.x * TOK;
  const float* e2s = e2 + (size_t)s * NBINS;
  const unsigned short* bhp = cb_h + (size_t)s * (32 * 1024 * 8);
  const unsigned short* blp = cb_l + (size_t)s * (32 * 1024 * 8);

  // ---- A build: -2*r as bf16 hi/lo into LDS ----
  {
    int row = thr >> 2, d0 = (thr & 3) << 6;
    const float* rrow = res + (size_t)(m0 + row) * DC + d0;
#pragma unroll
    for (int c = 0; c < 8; ++c) {
      float4 r0 = *reinterpret_cast<const float4*>(rrow + c * 8);
      float4 r1 = *reinterpret_cast<const float4*>(rrow + c * 8 + 4);
      float rv[8] = {r0.x, r0.y, r0.z, r0.w, r1.x, r1.y, r1.z, r1.w};
      unsigned short hh[8], ll[8];
#pragma unroll
      for (int j = 0; j < 8; ++j) {
        float xv = -2.0f * rv[j];
        unsigned short h = f2bf(xv);
        hh[j] = h; ll[j] = f2bf(xv - bf2f(h));
      }
      int k8 = (d0 >> 3) + c;
      store8s(a_hi + ((size_t)k8 * TOK + row) * 8, hh);
      store8s(a_lo + ((size_t)k8 * TOK + row) * 8, ll);
    }
  }
  m1s[thr] = 3.4028235e38f; m2s[thr] = 3.4028235e38f; i1s[thr] = 0;
  __syncthreads();

  for (int c = 0; c < 4; ++c) {
    const int bbase = w * 256 + c * 64;
    f32x4 acc[4][4];
#pragma unroll
    for (int nt = 0; nt < 4; ++nt) {
      float ev = e2s[bbase + nt * 16 + lc];
      f32x4 iv = {ev, ev, ev, ev};
#pragma unroll
      for (int rt = 0; rt < 4; ++rt) acc[rt][nt] = iv;
    }
#pragma unroll 2
    for (int kstep = 0; kstep < 8; ++kstep) {
      short8v ah[4], al[4];
#pragma unroll
      for (int rt = 0; rt < 4; ++rt) {
        int off = ((kstep * 4 + lg) * TOK + rt * 16 + lc) * 8;
        ah[rt] = load8s(a_hi + off);
        al[rt] = load8s(a_lo + off);
      }
      short8v bh[4], bl[4];
#pragma unroll
      for (int nt = 0; nt < 4; ++nt) {
        size_t boff = ((size_t)(kstep * 4 + lg) * 1024 + bbase + nt * 16 + lc) * 8;
        bh[nt] = load8s(bhp + boff);
        bl[nt] = load8s(blp + boff);
      }
#pragma unroll
      for (int nt = 0; nt < 4; ++nt)
#pragma unroll
        for (int rt = 0; rt < 4; ++rt)
          acc[rt][nt] = __builtin_amdgcn_mfma_f32_16x16x32_bf16(ah[rt], bh[nt], acc[rt][nt], 0, 0, 0);
#pragma unroll
      for (int nt = 0; nt < 4; ++nt)
#pragma unroll
        for (int rt = 0; rt < 4; ++rt)
          acc[rt][nt] = __builtin_amdgcn_mfma_f32_16x16x32_bf16(ah[rt], bl[nt], acc[rt][nt], 0, 0, 0);
#pragma unroll
      for (int nt = 0; nt < 4; ++nt)
#pragma unroll
        for (int rt = 0; rt < 4; ++rt)
          acc[rt][nt] = __builtin_amdgcn_mfma_f32_16x16x32_bf16(al[rt], bh[nt], acc[rt][nt], 0, 0, 0);
    }
    // fold this chunk into per-wave LDS top-2 (bins ascending)
#pragma unroll
    for (int rt = 0; rt < 4; ++rt)
#pragma unroll
      for (int reg = 0; reg < 4; ++reg) {
        float m1 = 3.4028235e38f, m2 = 3.4028235e38f; int i1 = 0;
#pragma unroll
        for (int nt = 0; nt < 4; ++nt) {
          float v = acc[rt][nt][reg];
          int b = bbase + nt * 16 + lc;
          if (v < m1) { m2 = m1; m1 = v; i1 = b; }
          else m2 = fminf(m2, v);
        }
#pragma unroll
        for (int msk = 1; msk < 16; msk <<= 1) {
          float om1 = __shfl_xor(m1, msk, 64);
          float om2 = __shfl_xor(m2, msk, 64);
          int   oi1 = __shfl_xor(i1, msk, 64);
          if (om1 < m1 || (om1 == m1 && oi1 < i1)) { m2 = fminf(m1, om2); m1 = om1; i1 = oi1; }
          else m2 = fminf(m2, om1);
        }
        if (lc == 0) {
          int sidx = w * TOK + rt * 16 + lg * 4 + reg;
          float pm1 = m1s[sidx], pm2 = m2s[sidx]; int pi1 = i1s[sidx];
          if (m1 < pm1 || (m1 == pm1 && i1 < pi1)) {
            m1s[sidx] = m1; m2s[sidx] = fminf(pm1, m2); i1s[sidx] = i1;
          } else {
            m2s[sidx] = fminf(pm2, m1);
          }
        }
      }
  }
  __syncthreads();
  // final per-row merge across waves -> winner + margin flag -> global
  if (thr < TOK) {
    float m1 = m1s[thr], m2 = m2s[thr]; int i1 = i1s[thr];
#pragma unroll
    for (int ww = 1; ww < 4; ++ww) {
      float om1 = m1s[ww * TOK + thr], om2 = m2s[ww * TOK + thr];
      int oi1 = i1s[ww * TOK + thr];
      if (om1 < m1 || (om1 == m1 && oi1 < i1)) { m2 = fminf(m1, om2); m1 = om1; i1 = oi1; }
      else m2 = fminf(m2, om1);
    }
    win_g[m0 + thr] = i1;
    flag_g[m0 + thr] = (m2 - m1 < MARGIN) ? 1 : 0;
  }
}

// ---------------- K2b: per-stage fix: np re-rank + np residual update ----------------
__global__ __launch_bounds__(256) void fix_kernel(
    const float* __restrict__ cb, const float* __restrict__ e2,
    const int* __restrict__ win_g, const int* __restrict__ flag_g,
    float* __restrict__ res, float* __restrict__ idx_f, double* __restrict__ partial,
    int s) {
  __shared__ int win_l[TOK], flag_l[TOK];
  __shared__ __align__(16) float rrow_s[256];
  __shared__ float redf[4];
  __shared__ int   redi[4];
  __shared__ double wsum[4];
  const int thr = threadIdx.x;
  const int lane = thr & 63;
  const int w = thr >> 6;
  const int m0 = blockIdx.x * TOK;
  const float* cbs = cb + (size_t)s * NBINS * DC;
  const float* e2s = e2 + (size_t)s * NBINS;
  double sqacc = 0.0;

  if (thr < TOK) { win_l[thr] = win_g[m0 + thr]; flag_l[thr] = flag_g[m0 + thr]; }
  __syncthreads();
  // ---- np-bit re-rank for flagged rows (rare; uniform branch) ----
  for (int row = 0; row < TOK; ++row) {
    if (!flag_l[row]) continue;
    if (thr < 64)
      reinterpret_cast<float4*>(rrow_s)[thr] =
          reinterpret_cast<const float4*>(res + (size_t)(m0 + row) * DC)[thr];
    __syncthreads();
    float r2 = np_sumsq256(rrow_s);
    float best = 3.4028235e38f; int bb = 0;
#pragma unroll
    for (int jj = 0; jj < 4; ++jj) {
      int b = thr * 4 + jj;
      const float4* e4 = reinterpret_cast<const float4*>(cbs + (size_t)b * DC);
      const float4* r4 = reinterpret_cast<const float4*>(rrow_s);
      float accv = 0.f;
      for (int q = 0; q < 64; ++q) {   // d ascending: sgemm-chain bits
        float4 ev = e4[q], rv = r4[q];
        accv = fmaf(rv.x, ev.x, accv);
        accv = fmaf(rv.y, ev.y, accv);
        accv = fmaf(rv.z, ev.z, accv);
        accv = fmaf(rv.w, ev.w, accv);
      }
      {
#pragma clang fp contract(off)
        float t = r2 - 2.0f * accv;
        float dist = t + e2s[b];
        if (dist < best) { best = dist; bb = b; }
      }
    }
#pragma unroll
    for (int msk = 1; msk < 64; msk <<= 1) {
      float ov = __shfl_xor(best, msk, 64);
      int   ob = __shfl_xor(bb, msk, 64);
      if (ov < best || (ov == best && ob < bb)) { best = ov; bb = ob; }
    }
    if (lane == 0) { redf[w] = best; redi[w] = bb; }
    __syncthreads();
    if (thr == 0) {
      float bs = redf[0]; int bfin = redi[0];
#pragma unroll
      for (int ww = 1; ww < 4; ++ww)
        if (redf[ww] < bs || (redf[ww] == bs && redi[ww] < bfin)) { bs = redf[ww]; bfin = redi[ww]; }
      win_l[row] = bfin;
    }
    __syncthreads();
  }
  // ---- residual update (np state bits) + commit acc ----
  {
    int row = thr >> 2, d0 = (thr & 3) << 6;
    int wbin = win_l[row];
    const float* erow = cbs + (size_t)wbin * DC + d0;
    float* rrow = res + (size_t)(m0 + row) * DC + d0;
#pragma unroll
    for (int c = 0; c < 8; ++c) {
      float4 r0 = *reinterpret_cast<const float4*>(rrow + c * 8);
      float4 r1 = *reinterpret_cast<const float4*>(rrow + c * 8 + 4);
      float4 e0 = *reinterpret_cast<const float4*>(erow + c * 8);
      float4 e1 = *reinterpret_cast<const float4*>(erow + c * 8 + 4);
      float nv[8] = {r0.x - e0.x, r0.y - e0.y, r0.z - e0.z, r0.w - e0.w,
                     r1.x - e1.x, r1.y - e1.y, r1.z - e1.z, r1.w - e1.w};
#pragma unroll
      for (int j = 0; j < 8; ++j) sqacc += (double)nv[j] * nv[j];
      *reinterpret_cast<float4*>(rrow + c * 8) = (float4){nv[0], nv[1], nv[2], nv[3]};
      *reinterpret_cast<float4*>(rrow + c * 8 + 4) = (float4){nv[4], nv[5], nv[6], nv[7]};
    }
    if (thr < TOK) idx_f[(size_t)s * NTOK + m0 + thr] = (float)win_l[thr];
  }
  // deterministic per-block commit partial (fp64)
#pragma unroll
  for (int msk = 1; msk < 64; msk <<= 1) sqacc += __shfl_xor(sqacc, msk, 64);
  if (lane == 0) wsum[w] = sqacc;
  __syncthreads();
  if (thr == 0) {
    double t = 0.0;
#pragma unroll
    for (int ww = 0; ww < 4; ++ww) t += wsum[ww];
    partial[(size_t)s * STG_BLOCKS + blockIdx.x] = t;
  }
}

// ---------------- K4: finalize commit loss (fixed order, 8*512 partials) ----------------
__global__ void finalize_kernel(const double* __restrict__ partial, float* __restrict__ out_last) {
  __shared__ double acc_s[64];
  int t = threadIdx.x;
  double a = 0.0;
  for (int i = 0; i < 64; ++i) a += partial[(size_t)t * 64 + i];
  acc_s[t] = a;
  __syncthreads();
  if (t == 0) {
    double tot = 0.0;
    for (int i = 0; i < 64; ++i) tot += acc_s[i];
    out_last[0] = (float)(0.1 * tot / 8388608.0);
  }
}

// ---------------- K3: out-projection GEMM from gathered quantized ----------------
__global__ __launch_bounds__(256) void out_proj_kernel(
    const float* __restrict__ cb, const float* __restrict__ idx_f,
    const float* __restrict__ out_w, const float* __restrict__ out_b,
    float* __restrict__ out) {
  __shared__ __align__(16) float aT[DCH][68];
  __shared__ __align__(16) float bT[DCH][68];
  __shared__ int idx_l[NQ][64];
  const int thr = threadIdx.x;
  const int tx = thr & 15, ty = thr >> 4;
  const int m0 = blockIdx.x * 64, n0 = blockIdx.y * 64;
#pragma unroll
  for (int i = 0; i < 2; ++i) {
    int q = thr + 256 * i;
    int s = q >> 6, m = q & 63;
    idx_l[s][m] = (int)idx_f[(size_t)s * NTOK + m0 + m];
  }
  float acc[4][4] = {};
  for (int kc = 0; kc < DC; kc += DCH) {
    __syncthreads();
#pragma unroll
    for (int i = 0; i < 2; ++i) {
      int q = thr + 256 * i;
      int m = q >> 3, kk = (q & 7) << 2;
      float4 v = {0.f, 0.f, 0.f, 0.f};
#pragma unroll
      for (int s = 0; s < NQ; ++s) {
        const float4 e = *reinterpret_cast<const float4*>(
            cb + ((size_t)s * NBINS + idx_l[s][m]) * DC + kc + kk);
        v.x += e.x; v.y += e.y; v.z += e.z; v.w += e.w;
      }
      aT[kk + 0][m] = v.x; aT[kk + 1][m] = v.y; aT[kk + 2][m] = v.z; aT[kk + 3][m] = v.w;
      float4 wv = *reinterpret_cast<const float4*>(out_w + (size_t)(n0 + m) * DC + kc + kk);
      bT[kk + 0][m] = wv.x; bT[kk + 1][m] = wv.y; bT[kk + 2][m] = wv.z; bT[kk + 3][m] = wv.w;
    }
    __syncthreads();
#pragma unroll 8
    for (int d = 0; d < DCH; ++d) {
      float4 a = *reinterpret_cast<const float4*>(&aT[d][ty * 4]);
      float4 b = *reinterpret_cast<const float4*>(&bT[d][tx * 4]);
      float av[4] = {a.x, a.y, a.z, a.w};
      float bv[4] = {b.x, b.y, b.z, b.w};
#pragma unroll
      for (int i = 0; i < 4; ++i)
#pragma unroll
        for (int j = 0; j < 4; ++j) acc[i][j] = fmaf(av[i], bv[j], acc[i][j]);
    }
  }
#pragma unroll
  for (int i = 0; i < 4; ++i) {
    int m = m0 + ty * 4 + i, n = n0 + tx * 4;
    float4 o;
    o.x = acc[i][0] + out_b[n + 0];
    o.y = acc[i][1] + out_b[n + 1];
    o.z = acc[i][2] + out_b[n + 2];
    o.w = acc[i][3] + out_b[n + 3];
    *reinterpret_cast<float4*>(out + (size_t)m * D_IN + n) = o;
  }
}

extern "C" void kernel_launch(void* const* d_in, const int* in_sizes, int n_in,
                              void* d_out, int out_size, void* d_ws, size_t ws_size,
                              hipStream_t stream) {
  (void)in_sizes; (void)n_in; (void)out_size; (void)d_ws; (void)ws_size;
  const float* x     = (const float*)d_in[0];
  const float* in_w  = (const float*)d_in[1];
  const float* in_b  = (const float*)d_in[2];
  const float* out_w = (const float*)d_in[3];
  const float* out_b = (const float*)d_in[4];
  const float* cb    = (const float*)d_in[5];
  float* out = (float*)d_out;
  // d_out scratch layout (consumed before out_proj overwrites [0,16.7M)):
  float* res    = out;                                  // 8,388,608 f32 residual
  float* e2     = out + 8388608;                        // 8192 f32 (np bits)
  double* part  = (double*)(out + 8404992);             // 4096 f64
  unsigned short* cb_h = (unsigned short*)(out + 9000000);   // 2,097,152 bf16
  unsigned short* cb_l = (unsigned short*)(out + 10500000);  // 2,097,152 bf16
  int* win_g   = (int*)(out + 11600000);                // 32768 int
  int* flag_g  = (int*)(out + 11700000);                // 32768 int
  float* idx_f  = out + 16777216;                       // 262,144 f32
  float* c_out  = out + 17039360;                       // 1 f32

  hipLaunchKernelGGL(e2_np_kernel, dim3(32), dim3(256), 0, stream, cb, e2);
  hipLaunchKernelGGL(presplit_kernel, dim3(1024), dim3(256), 0, stream, cb, cb_h, cb_l);
  hipLaunchKernelGGL(in_proj_kernel, dim3(512, 4), dim3(256), 0, stream, x, in_w, in_b, res);
  for (int s = 0; s < NQ; ++s) {
    hipLaunchKernelGGL(score_kernel, dim3(STG_BLOCKS), dim3(256), 0, stream,
                       e2, cb_h, cb_l, res, win_g, flag_g, s);
    hipLaunchKernelGGL(fix_kernel, dim3(STG_BLOCKS), dim3(256), 0, stream,
                       cb, e2, win_g, flag_g, res, idx_f, part, s);
  }
  hipLaunchKernelGGL(finalize_kernel, dim3(1), dim3(64), 0, stream, part, c_out);
  hipLaunchKernelGGL(out_proj_kernel, dim3(512, 8), dim3(256), 0, stream, cb, idx_f, out_w, out_b, out);
}

// Round 16
// 1491.076 us; speedup vs baseline: 1.3998x; 1.0472x over previous
//
#include <hip/hip_runtime.h>
#include <math.h>

#define DC 256
#define NBINS 1024
#define NQ 8
#define NTOK 32768      // B*T
#define D_IN 512
#define DCH 32
#define TOK 64          // tokens per stage-block -> 512 blocks/stage
#define STG_BLOCKS (NTOK / TOK)
#define MARGIN 5e-3f    // fast(MFMA) top-2 gap below which we re-rank with np bits

typedef __attribute__((ext_vector_type(8))) short short8v;   // 8 bf16 (4 VGPR)
typedef __attribute__((ext_vector_type(4))) float f32x4;

// ---- bf16 helpers (RNE, matches hw cvt) ----
__device__ __forceinline__ unsigned short f2bf(float x) {
  unsigned u = __float_as_uint(x);
  return (unsigned short)((u + 0x7fffu + ((u >> 16) & 1u)) >> 16);
}
__device__ __forceinline__ float bf2f(unsigned short h) {
  return __uint_as_float(((unsigned)h) << 16);
}
__device__ __forceinline__ void store8s(unsigned short* dst, const unsigned short* v) {
  uint4 u;
  u.x = v[0] | ((unsigned)v[1] << 16); u.y = v[2] | ((unsigned)v[3] << 16);
  u.z = v[4] | ((unsigned)v[5] << 16); u.w = v[6] | ((unsigned)v[7] << 16);
  *reinterpret_cast<uint4*>(dst) = u;
}
__device__ __forceinline__ short8v pack8s(const unsigned short* v) {
  uint4 u;
  u.x = v[0] | ((unsigned)v[1] << 16); u.y = v[2] | ((unsigned)v[3] << 16);
  u.z = v[4] | ((unsigned)v[5] << 16); u.w = v[6] | ((unsigned)v[7] << 16);
  return __builtin_bit_cast(short8v, u);
}
__device__ __forceinline__ short8v load8s(const unsigned short* p) {
  return __builtin_bit_cast(short8v, *reinterpret_cast<const float4*>(p));
}

// ---- numpy pairwise_sum bit-emulation (8 accumulators, 128-block) ----
__device__ __forceinline__ float np_sumsq128(const float* a) {
#pragma clang fp contract(off)
  float r0 = a[0] * a[0], r1 = a[1] * a[1], r2 = a[2] * a[2], r3 = a[3] * a[3];
  float r4 = a[4] * a[4], r5 = a[5] * a[5], r6 = a[6] * a[6], r7 = a[7] * a[7];
  for (int i = 8; i < 128; i += 8) {
    r0 += a[i + 0] * a[i + 0]; r1 += a[i + 1] * a[i + 1];
    r2 += a[i + 2] * a[i + 2]; r3 += a[i + 3] * a[i + 3];
    r4 += a[i + 4] * a[i + 4]; r5 += a[i + 5] * a[i + 5];
    r6 += a[i + 6] * a[i + 6]; r7 += a[i + 7] * a[i + 7];
  }
  return ((r0 + r1) + (r2 + r3)) + ((r4 + r5) + (r6 + r7));
}
__device__ __forceinline__ float np_sumsq256(const float* a) {
#pragma clang fp contract(off)
  float lo = np_sumsq128(a);
  float hi = np_sumsq128(a + 128);
  return lo + hi;
}

// ---------------- K0: codebook squared norms, np-pairwise bits ----------------
__global__ void e2_np_kernel(const float* __restrict__ cb, float* __restrict__ e2) {
  int b = blockIdx.x * 256 + threadIdx.x;
  e2[b] = np_sumsq256(cb + (size_t)b * DC);
}

// ---------------- K0b: codebook bf16 hi/lo pre-split ----------------
// layout: [s][k8 0..31][bin 0..1023][8] bf16
__global__ void presplit_kernel(const float* __restrict__ cb,
                                unsigned short* __restrict__ cb_h,
                                unsigned short* __restrict__ cb_l) {
  int id = blockIdx.x * 256 + threadIdx.x;   // (s*32+k8)*1024 + bin
  int sk = id >> 10, bin = id & 1023;
  int s = sk >> 5, k8 = sk & 31;
  const float* src = cb + ((size_t)s * NBINS + bin) * DC + k8 * 8;
  unsigned short hh[8], ll[8];
#pragma unroll
  for (int j = 0; j < 8; ++j) {
    float x = src[j];
    unsigned short h = f2bf(x);
    hh[j] = h;
    ll[j] = f2bf(x - bf2f(h));
  }
  store8s(cb_h + (size_t)id * 8, hh);
  store8s(cb_l + (size_t)id * 8, ll);
}

// ---------------- K1: in-projection, OpenBLAS-sgemm bit-emulation ----------------
__global__ __launch_bounds__(256) void in_proj_kernel(
    const float* __restrict__ x, const float* __restrict__ in_w,
    const float* __restrict__ in_b, float* __restrict__ res) {
  __shared__ __align__(16) float aT[DCH][68];
  __shared__ __align__(16) float bT[DCH][68];
  const int thr = threadIdx.x;
  const int tx = thr & 15, ty = thr >> 4;
  const int m0 = blockIdx.x * 64, n0 = blockIdx.y * 64;
  float acc[4][4] = {};
  float s1[4][4] = {};
  for (int kc = 0; kc < D_IN; kc += DCH) {
    if (kc == 384) {
#pragma unroll
      for (int i = 0; i < 4; ++i)
#pragma unroll
        for (int j = 0; j < 4; ++j) { s1[i][j] = acc[i][j]; acc[i][j] = 0.f; }
    }
    __syncthreads();
#pragma unroll
    for (int i = 0; i < 2; ++i) {
      int q = thr + 256 * i;
      int m = q >> 3, kk = (q & 7) << 2;
      float4 v = *reinterpret_cast<const float4*>(x + (size_t)(m0 + m) * D_IN + kc + kk);
      aT[kk + 0][m] = v.x; aT[kk + 1][m] = v.y; aT[kk + 2][m] = v.z; aT[kk + 3][m] = v.w;
      float4 w = *reinterpret_cast<const float4*>(in_w + (size_t)(n0 + m) * D_IN + kc + kk);
      bT[kk + 0][m] = w.x; bT[kk + 1][m] = w.y; bT[kk + 2][m] = w.z; bT[kk + 3][m] = w.w;
    }
    __syncthreads();
#pragma unroll 8
    for (int d = 0; d < DCH; ++d) {
      float4 a = *reinterpret_cast<const float4*>(&aT[d][ty * 4]);
      float4 b = *reinterpret_cast<const float4*>(&bT[d][tx * 4]);
      float av[4] = {a.x, a.y, a.z, a.w};
      float bv[4] = {b.x, b.y, b.z, b.w};
#pragma unroll
      for (int i = 0; i < 4; ++i)
#pragma unroll
        for (int j = 0; j < 4; ++j) acc[i][j] = fmaf(av[i], bv[j], acc[i][j]);
    }
  }
#pragma unroll
  for (int i = 0; i < 4; ++i) {
    int m = m0 + ty * 4 + i, n = n0 + tx * 4;
    float4 hv;
#pragma unroll
    for (int j = 0; j < 4; ++j) {
#pragma clang fp contract(off)
      float c = s1[i][j] + acc[i][j];
      float pre = c + in_b[n + j];
      ((float*)&hv)[j] = tanhf(pre);
    }
    *reinterpret_cast<float4*>(res + (size_t)m * DC + n) = hv;
  }
}

// ---------------- K2a: per-stage MFMA scoring ----------------
__global__ __launch_bounds__(256, 2) void score_kernel(
    const float* __restrict__ e2,
    const unsigned short* __restrict__ cb_h, const unsigned short* __restrict__ cb_l,
    const float* __restrict__ res, int* __restrict__ win_g, int* __restrict__ flag_g,
    int s) {
  __shared__ __align__(16) unsigned short a_hi[32 * TOK * 8];  // 32KB
  __shared__ __align__(16) unsigned short a_lo[32 * TOK * 8];  // 32KB
  __shared__ float m1s[4 * TOK], m2s[4 * TOK];
  __shared__ int   i1s[4 * TOK];

  const int thr = threadIdx.x;
  const int lane = thr & 63;
  const int w = thr >> 6;        // wave 0..3 -> bins [w*256, w*256+256)
  const int lg = lane >> 4;      // k-subgroup (A/B), row-subgroup (C)
  const int lc = lane & 15;      // A row-in-tile / B,C col(bin)-in-tile
  const int m0 = blockIdx.x * TOK;
  const float* e2s = e2 + (size_t)s * NBINS;
  const unsigned short* bhp = cb_h + (size_t)s * (32 * 1024 * 8);
  const unsigned short* blp = cb_l + (size_t)s * (32 * 1024 * 8);

  // ---- A build: -2*r as bf16 hi/lo into LDS ----
  {
    int row = thr >> 2, d0 = (thr & 3) << 6;
    const float* rrow = res + (size_t)(m0 + row) * DC + d0;
#pragma unroll
    for (int c = 0; c < 8; ++c) {
      float4 r0 = *reinterpret_cast<const float4*>(rrow + c * 8);
      float4 r1 = *reinterpret_cast<const float4*>(rrow + c * 8 + 4);
      float rv[8] = {r0.x, r0.y, r0.z, r0.w, r1.x, r1.y, r1.z, r1.w};
      unsigned short hh[8], ll[8];
#pragma unroll
      for (int j = 0; j < 8; ++j) {
        float xv = -2.0f * rv[j];
        unsigned short h = f2bf(xv);
        hh[j] = h; ll[j] = f2bf(xv - bf2f(h));
      }
      int k8 = (d0 >> 3) + c;
      store8s(a_hi + ((size_t)k8 * TOK + row) * 8, hh);
      store8s(a_lo + ((size_t)k8 * TOK + row) * 8, ll);
    }
  }
  m1s[thr] = 3.4028235e38f; m2s[thr] = 3.4028235e38f; i1s[thr] = 0;
  __syncthreads();

  for (int c = 0; c < 4; ++c) {
    const int bbase = w * 256 + c * 64;
    f32x4 acc[4][4];
#pragma unroll
    for (int nt = 0; nt < 4; ++nt) {
      float ev = e2s[bbase + nt * 16 + lc];
      f32x4 iv = {ev, ev, ev, ev};
#pragma unroll
      for (int rt = 0; rt < 4; ++rt) acc[rt][nt] = iv;
    }
#pragma unroll 2
    for (int kstep = 0; kstep < 8; ++kstep) {
      short8v ah[4], al[4];
#pragma unroll
      for (int rt = 0; rt < 4; ++rt) {
        int off = ((kstep * 4 + lg) * TOK + rt * 16 + lc) * 8;
        ah[rt] = load8s(a_hi + off);
        al[rt] = load8s(a_lo + off);
      }
      short8v bh[4], bl[4];
#pragma unroll
      for (int nt = 0; nt < 4; ++nt) {
        size_t boff = ((size_t)(kstep * 4 + lg) * 1024 + bbase + nt * 16 + lc) * 8;
        bh[nt] = load8s(bhp + boff);
        bl[nt] = load8s(blp + boff);
      }
#pragma unroll
      for (int nt = 0; nt < 4; ++nt)
#pragma unroll
        for (int rt = 0; rt < 4; ++rt)
          acc[rt][nt] = __builtin_amdgcn_mfma_f32_16x16x32_bf16(ah[rt], bh[nt], acc[rt][nt], 0, 0, 0);
#pragma unroll
      for (int nt = 0; nt < 4; ++nt)
#pragma unroll
        for (int rt = 0; rt < 4; ++rt)
          acc[rt][nt] = __builtin_amdgcn_mfma_f32_16x16x32_bf16(ah[rt], bl[nt], acc[rt][nt], 0, 0, 0);
#pragma unroll
      for (int nt = 0; nt < 4; ++nt)
#pragma unroll
        for (int rt = 0; rt < 4; ++rt)
          acc[rt][nt] = __builtin_amdgcn_mfma_f32_16x16x32_bf16(al[rt], bh[nt], acc[rt][nt], 0, 0, 0);
    }
    // fold this chunk into per-wave LDS top-2 (bins ascending)
#pragma unroll
    for (int rt = 0; rt < 4; ++rt)
#pragma unroll
      for (int reg = 0; reg < 4; ++reg) {
        float m1 = 3.4028235e38f, m2 = 3.4028235e38f; int i1 = 0;
#pragma unroll
        for (int nt = 0; nt < 4; ++nt) {
          float v = acc[rt][nt][reg];
          int b = bbase + nt * 16 + lc;
          if (v < m1) { m2 = m1; m1 = v; i1 = b; }
          else m2 = fminf(m2, v);
        }
#pragma unroll
        for (int msk = 1; msk < 16; msk <<= 1) {
          float om1 = __shfl_xor(m1, msk, 64);
          float om2 = __shfl_xor(m2, msk, 64);
          int   oi1 = __shfl_xor(i1, msk, 64);
          if (om1 < m1 || (om1 == m1 && oi1 < i1)) { m2 = fminf(m1, om2); m1 = om1; i1 = oi1; }
          else m2 = fminf(m2, om1);
        }
        if (lc == 0) {
          int sidx = w * TOK + rt * 16 + lg * 4 + reg;
          float pm1 = m1s[sidx], pm2 = m2s[sidx]; int pi1 = i1s[sidx];
          if (m1 < pm1 || (m1 == pm1 && i1 < pi1)) {
            m1s[sidx] = m1; m2s[sidx] = fminf(pm1, m2); i1s[sidx] = i1;
          } else {
            m2s[sidx] = fminf(pm2, m1);
          }
        }
      }
  }
  __syncthreads();
  // final per-row merge across waves -> winner + margin flag -> global
  if (thr < TOK) {
    float m1 = m1s[thr], m2 = m2s[thr]; int i1 = i1s[thr];
#pragma unroll
    for (int ww = 1; ww < 4; ++ww) {
      float om1 = m1s[ww * TOK + thr], om2 = m2s[ww * TOK + thr];
      int oi1 = i1s[ww * TOK + thr];
      if (om1 < m1 || (om1 == m1 && oi1 < i1)) { m2 = fminf(m1, om2); m1 = om1; i1 = oi1; }
      else m2 = fminf(m2, om1);
    }
    win_g[m0 + thr] = i1;
    flag_g[m0 + thr] = (m2 - m1 < MARGIN) ? 1 : 0;
  }
}

// ---------------- K2b: per-stage fix: np re-rank + np residual update ----------------
__global__ __launch_bounds__(256) void fix_kernel(
    const float* __restrict__ cb, const float* __restrict__ e2,
    const int* __restrict__ win_g, const int* __restrict__ flag_g,
    float* __restrict__ res, float* __restrict__ idx_f, double* __restrict__ partial,
    int s) {
  __shared__ int win_l[TOK], flag_l[TOK];
  __shared__ __align__(16) float rrow_s[256];
  __shared__ float redf[4];
  __shared__ int   redi[4];
  __shared__ double wsum[4];
  const int thr = threadIdx.x;
  const int lane = thr & 63;
  const int w = thr >> 6;
  const int m0 = blockIdx.x * TOK;
  const float* cbs = cb + (size_t)s * NBINS * DC;
  const float* e2s = e2 + (size_t)s * NBINS;
  double sqacc = 0.0;

  if (thr < TOK) { win_l[thr] = win_g[m0 + thr]; flag_l[thr] = flag_g[m0 + thr]; }
  __syncthreads();
  // ---- np-bit re-rank for flagged rows (rare; uniform branch) ----
  for (int row = 0; row < TOK; ++row) {
    if (!flag_l[row]) continue;
    if (thr < 64)
      reinterpret_cast<float4*>(rrow_s)[thr] =
          reinterpret_cast<const float4*>(res + (size_t)(m0 + row) * DC)[thr];
    __syncthreads();
    float r2 = np_sumsq256(rrow_s);
    float best = 3.4028235e38f; int bb = 0;
#pragma unroll
    for (int jj = 0; jj < 4; ++jj) {
      int b = thr * 4 + jj;
      const float4* e4 = reinterpret_cast<const float4*>(cbs + (size_t)b * DC);
      const float4* r4 = reinterpret_cast<const float4*>(rrow_s);
      float accv = 0.f;
      for (int q = 0; q < 64; ++q) {   // d ascending: sgemm-chain bits
        float4 ev = e4[q], rv = r4[q];
        accv = fmaf(rv.x, ev.x, accv);
        accv = fmaf(rv.y, ev.y, accv);
        accv = fmaf(rv.z, ev.z, accv);
        accv = fmaf(rv.w, ev.w, accv);
      }
      {
#pragma clang fp contract(off)
        float t = r2 - 2.0f * accv;
        float dist = t + e2s[b];
        if (dist < best) { best = dist; bb = b; }
      }
    }
#pragma unroll
    for (int msk = 1; msk < 64; msk <<= 1) {
      float ov = __shfl_xor(best, msk, 64);
      int   ob = __shfl_xor(bb, msk, 64);
      if (ov < best || (ov == best && ob < bb)) { best = ov; bb = ob; }
    }
    if (lane == 0) { redf[w] = best; redi[w] = bb; }
    __syncthreads();
    if (thr == 0) {
      float bs = redf[0]; int bfin = redi[0];
#pragma unroll
      for (int ww = 1; ww < 4; ++ww)
        if (redf[ww] < bs || (redf[ww] == bs && redi[ww] < bfin)) { bs = redf[ww]; bfin = redi[ww]; }
      win_l[row] = bfin;
    }
    __syncthreads();
  }
  // ---- residual update (np state bits) + commit acc ----
  {
    int row = thr >> 2, d0 = (thr & 3) << 6;
    int wbin = win_l[row];
    const float* erow = cbs + (size_t)wbin * DC + d0;
    float* rrow = res + (size_t)(m0 + row) * DC + d0;
#pragma unroll
    for (int c = 0; c < 8; ++c) {
      float4 r0 = *reinterpret_cast<const float4*>(rrow + c * 8);
      float4 r1 = *reinterpret_cast<const float4*>(rrow + c * 8 + 4);
      float4 e0 = *reinterpret_cast<const float4*>(erow + c * 8);
      float4 e1 = *reinterpret_cast<const float4*>(erow + c * 8 + 4);
      float nv[8] = {r0.x - e0.x, r0.y - e0.y, r0.z - e0.z, r0.w - e0.w,
                     r1.x - e1.x, r1.y - e1.y, r1.z - e1.z, r1.w - e1.w};
#pragma unroll
      for (int j = 0; j < 8; ++j) sqacc += (double)nv[j] * nv[j];
      *reinterpret_cast<float4*>(rrow + c * 8) = (float4){nv[0], nv[1], nv[2], nv[3]};
      *reinterpret_cast<float4*>(rrow + c * 8 + 4) = (float4){nv[4], nv[5], nv[6], nv[7]};
    }
    if (thr < TOK) idx_f[(size_t)s * NTOK + m0 + thr] = (float)win_l[thr];
  }
  // deterministic per-block commit partial (fp64)
#pragma unroll
  for (int msk = 1; msk < 64; msk <<= 1) sqacc += __shfl_xor(sqacc, msk, 64);
  if (lane == 0) wsum[w] = sqacc;
  __syncthreads();
  if (thr == 0) {
    double t = 0.0;
#pragma unroll
    for (int ww = 0; ww < 4; ++ww) t += wsum[ww];
    partial[(size_t)s * STG_BLOCKS + blockIdx.x] = t;
  }
}

// ---------------- K4: finalize commit loss (fixed order, 8*512 partials) ----------------
__global__ void finalize_kernel(const double* __restrict__ partial, float* __restrict__ out_last) {
  __shared__ double acc_s[64];
  int t = threadIdx.x;
  double a = 0.0;
  for (int i = 0; i < 64; ++i) a += partial[(size_t)t * 64 + i];
  acc_s[t] = a;
  __syncthreads();
  if (t == 0) {
    double tot = 0.0;
    for (int i = 0; i < 64; ++i) tot += acc_s[i];
    out_last[0] = (float)(0.1 * tot / 8388608.0);
  }
}

// ---------------- K3: out-projection via 3-pass bf16 hi/lo MFMA ----------------
// out[m][n] = q[m].out_w[n] + out_b[n], q = sum_s cb[s][idx_s[m]].
// 32 tokens/block; A(q hi/lo) in LDS; B(out_w) converted hi/lo on the fly
// (global presplit would race with this kernel's own output writes).
__global__ __launch_bounds__(256) void out_proj_kernel(
    const float* __restrict__ cb, const float* __restrict__ idx_f,
    const float* __restrict__ out_w, const float* __restrict__ out_b,
    float* __restrict__ out) {
  __shared__ __align__(16) unsigned short a_hi[32 * 32 * 8];  // 16KB
  __shared__ __align__(16) unsigned short a_lo[32 * 32 * 8];  // 16KB
  const int thr = threadIdx.x;
  const int lane = thr & 63;
  const int w = thr >> 6;        // wave 0..3 -> n in [w*128, w*128+128)
  const int lg = lane >> 4;
  const int lc = lane & 15;
  const int m0 = blockIdx.x * 32;

  // ---- gather q = sum_s cb[s][idx_s[m]] (fp32), hi/lo split into LDS ----
  {
    int row = thr >> 3, d0 = (thr & 7) << 5;   // 8 threads/row, 32 d each
    int m = m0 + row;
    int idxs[NQ];
#pragma unroll
    for (int s = 0; s < NQ; ++s) idxs[s] = (int)idx_f[(size_t)s * NTOK + m];
#pragma unroll
    for (int c = 0; c < 4; ++c) {
      int d = d0 + c * 8;
      float q[8] = {0.f, 0.f, 0.f, 0.f, 0.f, 0.f, 0.f, 0.f};
#pragma unroll
      for (int s = 0; s < NQ; ++s) {
        const float4* e4 = reinterpret_cast<const float4*>(
            cb + ((size_t)s * NBINS + idxs[s]) * DC + d);
        float4 e0 = e4[0], e1 = e4[1];
        q[0] += e0.x; q[1] += e0.y; q[2] += e0.z; q[3] += e0.w;
        q[4] += e1.x; q[5] += e1.y; q[6] += e1.z; q[7] += e1.w;
      }
      unsigned short hh[8], ll[8];
#pragma unroll
      for (int j = 0; j < 8; ++j) {
        unsigned short h = f2bf(q[j]);
        hh[j] = h; ll[j] = f2bf(q[j] - bf2f(h));
      }
      int k8 = d >> 3;
      store8s(a_hi + ((size_t)k8 * 32 + row) * 8, hh);
      store8s(a_lo + ((size_t)k8 * 32 + row) * 8, ll);
    }
  }
  __syncthreads();

  // ---- 3-pass hi/lo MFMA: acc starts at out_b ----
  f32x4 acc[2][8];
#pragma unroll
  for (int nt = 0; nt < 8; ++nt) {
    float bv = out_b[w * 128 + nt * 16 + lc];
    f32x4 iv = {bv, bv, bv, bv};
    acc[0][nt] = iv; acc[1][nt] = iv;
  }
#pragma unroll 2
  for (int kstep = 0; kstep < 8; ++kstep) {
    short8v ah[2], al[2];
#pragma unroll
    for (int rt = 0; rt < 2; ++rt) {
      int off = ((kstep * 4 + lg) * 32 + rt * 16 + lc) * 8;
      ah[rt] = load8s(a_hi + off);
      al[rt] = load8s(a_lo + off);
    }
#pragma unroll
    for (int nt = 0; nt < 8; ++nt) {
      int n = w * 128 + nt * 16 + lc;
      const float* wp = out_w + (size_t)n * DC + (kstep * 4 + lg) * 8;
      float4 w0 = *reinterpret_cast<const float4*>(wp);
      float4 w1 = *reinterpret_cast<const float4*>(wp + 4);
      float wv[8] = {w0.x, w0.y, w0.z, w0.w, w1.x, w1.y, w1.z, w1.w};
      unsigned short bhh[8], bll[8];
#pragma unroll
      for (int j = 0; j < 8; ++j) {
        unsigned short h = f2bf(wv[j]);
        bhh[j] = h; bll[j] = f2bf(wv[j] - bf2f(h));
      }
      short8v bh = pack8s(bhh), bl = pack8s(bll);
      acc[0][nt] = __builtin_amdgcn_mfma_f32_16x16x32_bf16(ah[0], bh, acc[0][nt], 0, 0, 0);
      acc[1][nt] = __builtin_amdgcn_mfma_f32_16x16x32_bf16(ah[1], bh, acc[1][nt], 0, 0, 0);
      acc[0][nt] = __builtin_amdgcn_mfma_f32_16x16x32_bf16(ah[0], bl, acc[0][nt], 0, 0, 0);
      acc[1][nt] = __builtin_amdgcn_mfma_f32_16x16x32_bf16(ah[1], bl, acc[1][nt], 0, 0, 0);
      acc[0][nt] = __builtin_amdgcn_mfma_f32_16x16x32_bf16(al[0], bh, acc[0][nt], 0, 0, 0);
      acc[1][nt] = __builtin_amdgcn_mfma_f32_16x16x32_bf16(al[1], bh, acc[1][nt], 0, 0, 0);
    }
  }
  // ---- C write: m = m0 + rt*16 + lg*4 + reg, n = w*128 + nt*16 + lc ----
#pragma unroll
  for (int rt = 0; rt < 2; ++rt)
#pragma unroll
    for (int nt = 0; nt < 8; ++nt) {
      int n = w * 128 + nt * 16 + lc;
#pragma unroll
      for (int reg = 0; reg < 4; ++reg) {
        int m = m0 + rt * 16 + lg * 4 + reg;
        out[(size_t)m * D_IN + n] = acc[rt][nt][reg];
      }
    }
}

extern "C" void kernel_launch(void* const* d_in, const int* in_sizes, int n_in,
                              void* d_out, int out_size, void* d_ws, size_t ws_size,
                              hipStream_t stream) {
  (void)in_sizes; (void)n_in; (void)out_size; (void)d_ws; (void)ws_size;
  const float* x     = (const float*)d_in[0];
  const float* in_w  = (const float*)d_in[1];
  const float* in_b  = (const float*)d_in[2];
  const float* out_w = (const float*)d_in[3];
  const float* out_b = (const float*)d_in[4];
  const float* cb    = (const float*)d_in[5];
  float* out = (float*)d_out;
  // d_out scratch layout (consumed before out_proj overwrites [0,16.7M)):
  float* res    = out;                                  // 8,388,608 f32 residual
  float* e2     = out + 8388608;                        // 8192 f32 (np bits)
  double* part  = (double*)(out + 8404992);             // 4096 f64
  unsigned short* cb_h = (unsigned short*)(out + 9000000);   // 2,097,152 bf16
  unsigned short* cb_l = (unsigned short*)(out + 10500000);  // 2,097,152 bf16
  int* win_g   = (int*)(out + 11600000);                // 32768 int
  int* flag_g  = (int*)(out + 11700000);                // 32768 int
  float* idx_f  = out + 16777216;                       // 262,144 f32
  float* c_out  = out + 17039360;                       // 1 f32

  hipLaunchKernelGGL(e2_np_kernel, dim3(32), dim3(256), 0, stream, cb, e2);
  hipLaunchKernelGGL(presplit_kernel, dim3(1024), dim3(256), 0, stream, cb, cb_h, cb_l);
  hipLaunchKernelGGL(in_proj_kernel, dim3(512, 4), dim3(256), 0, stream, x, in_w, in_b, res);
  for (int s = 0; s < NQ; ++s) {
    hipLaunchKernelGGL(score_kernel, dim3(STG_BLOCKS), dim3(256), 0, stream,
                       e2, cb_h, cb_l, res, win_g, flag_g, s);
    hipLaunchKernelGGL(fix_kernel, dim3(STG_BLOCKS), dim3(256), 0, stream,
                       cb, e2, win_g, flag_g, res, idx_f, part, s);
  }
  hipLaunchKernelGGL(finalize_kernel, dim3(1), dim3(64), 0, stream, part, c_out);
  hipLaunchKernelGGL(out_proj_kernel, dim3(1024), dim3(256), 0, stream, cb, idx_f, out_w, out_b, out);
}

// Round 17
// 1441.846 us; speedup vs baseline: 1.4476x; 1.0341x over previous
//
#include <hip/hip_runtime.h>
#include <math.h>

#define DC 256
#define NBINS 1024
#define NQ 8
#define NTOK 32768      // B*T
#define D_IN 512
#define DCH 32
#define TOK 64          // tokens per stage-block -> 512 blocks/stage
#define STG_BLOCKS (NTOK / TOK)
#define MARGIN 5e-3f    // fast(MFMA) top-2 gap below which we re-rank with np bits

typedef __attribute__((ext_vector_type(8))) short short8v;   // 8 bf16 (4 VGPR)
typedef __attribute__((ext_vector_type(4))) float f32x4;

// ---- bf16 helpers (RNE, matches hw cvt) ----
__device__ __forceinline__ unsigned short f2bf(float x) {
  unsigned u = __float_as_uint(x);
  return (unsigned short)((u + 0x7fffu + ((u >> 16) & 1u)) >> 16);
}
__device__ __forceinline__ float bf2f(unsigned short h) {
  return __uint_as_float(((unsigned)h) << 16);
}
__device__ __forceinline__ void store8s(unsigned short* dst, const unsigned short* v) {
  uint4 u;
  u.x = v[0] | ((unsigned)v[1] << 16); u.y = v[2] | ((unsigned)v[3] << 16);
  u.z = v[4] | ((unsigned)v[5] << 16); u.w = v[6] | ((unsigned)v[7] << 16);
  *reinterpret_cast<uint4*>(dst) = u;
}
__device__ __forceinline__ short8v pack8s(const unsigned short* v) {
  uint4 u;
  u.x = v[0] | ((unsigned)v[1] << 16); u.y = v[2] | ((unsigned)v[3] << 16);
  u.z = v[4] | ((unsigned)v[5] << 16); u.w = v[6] | ((unsigned)v[7] << 16);
  return __builtin_bit_cast(short8v, u);
}
__device__ __forceinline__ short8v load8s(const unsigned short* p) {
  return __builtin_bit_cast(short8v, *reinterpret_cast<const float4*>(p));
}

// ---- numpy pairwise_sum bit-emulation (8 accumulators, 128-block) ----
__device__ __forceinline__ float np_sumsq128(const float* a) {
#pragma clang fp contract(off)
  float r0 = a[0] * a[0], r1 = a[1] * a[1], r2 = a[2] * a[2], r3 = a[3] * a[3];
  float r4 = a[4] * a[4], r5 = a[5] * a[5], r6 = a[6] * a[6], r7 = a[7] * a[7];
  for (int i = 8; i < 128; i += 8) {
    r0 += a[i + 0] * a[i + 0]; r1 += a[i + 1] * a[i + 1];
    r2 += a[i + 2] * a[i + 2]; r3 += a[i + 3] * a[i + 3];
    r4 += a[i + 4] * a[i + 4]; r5 += a[i + 5] * a[i + 5];
    r6 += a[i + 6] * a[i + 6]; r7 += a[i + 7] * a[i + 7];
  }
  return ((r0 + r1) + (r2 + r3)) + ((r4 + r5) + (r6 + r7));
}
__device__ __forceinline__ float np_sumsq256(const float* a) {
#pragma clang fp contract(off)
  float lo = np_sumsq128(a);
  float hi = np_sumsq128(a + 128);
  return lo + hi;
}

// ---------------- K0: codebook squared norms, np-pairwise bits ----------------
__global__ void e2_np_kernel(const float* __restrict__ cb, float* __restrict__ e2) {
  int b = blockIdx.x * 256 + threadIdx.x;
  e2[b] = np_sumsq256(cb + (size_t)b * DC);
}

// ---------------- K0b: codebook bf16 hi/lo pre-split ----------------
// layout: [s][k8 0..31][bin 0..1023][8] bf16
__global__ void presplit_kernel(const float* __restrict__ cb,
                                unsigned short* __restrict__ cb_h,
                                unsigned short* __restrict__ cb_l) {
  int id = blockIdx.x * 256 + threadIdx.x;   // (s*32+k8)*1024 + bin
  int sk = id >> 10, bin = id & 1023;
  int s = sk >> 5, k8 = sk & 31;
  const float* src = cb + ((size_t)s * NBINS + bin) * DC + k8 * 8;
  unsigned short hh[8], ll[8];
#pragma unroll
  for (int j = 0; j < 8; ++j) {
    float x = src[j];
    unsigned short h = f2bf(x);
    hh[j] = h;
    ll[j] = f2bf(x - bf2f(h));
  }
  store8s(cb_h + (size_t)id * 8, hh);
  store8s(cb_l + (size_t)id * 8, ll);
}

// ---------------- K1: in-projection, OpenBLAS-sgemm bit-emulation ----------------
// 128x64 tile, 8x4 acc/thread (32 FMA per 3 ds_read_b128). Per-element chain
// order unchanged: d ascending, kc chunks ascending, OpenBLAS kc=384 split.
__global__ __launch_bounds__(256, 4) void in_proj_kernel(
    const float* __restrict__ x, const float* __restrict__ in_w,
    const float* __restrict__ in_b, float* __restrict__ res) {
  __shared__ __align__(16) float aT[DCH][132];
  __shared__ __align__(16) float bT[DCH][68];
  const int thr = threadIdx.x;
  const int tx = thr & 15, ty = thr >> 4;
  const int m0 = blockIdx.x * 128, n0 = blockIdx.y * 64;
  float acc[8][4] = {};
  float s1[8][4] = {};
  for (int kc = 0; kc < D_IN; kc += DCH) {
    if (kc == 384) {  // OpenBLAS kc-split
#pragma unroll
      for (int i = 0; i < 8; ++i)
#pragma unroll
        for (int j = 0; j < 4; ++j) { s1[i][j] = acc[i][j]; acc[i][j] = 0.f; }
    }
    __syncthreads();
#pragma unroll
    for (int i = 0; i < 4; ++i) {   // aT: 128 rows x 32 d = 1024 float4
      int q = thr + 256 * i;
      int m = q >> 3, kk = (q & 7) << 2;
      float4 v = *reinterpret_cast<const float4*>(x + (size_t)(m0 + m) * D_IN + kc + kk);
      aT[kk + 0][m] = v.x; aT[kk + 1][m] = v.y; aT[kk + 2][m] = v.z; aT[kk + 3][m] = v.w;
    }
#pragma unroll
    for (int i = 0; i < 2; ++i) {   // bT: 64 rows x 32 d = 512 float4
      int q = thr + 256 * i;
      int m = q >> 3, kk = (q & 7) << 2;
      float4 w = *reinterpret_cast<const float4*>(in_w + (size_t)(n0 + m) * D_IN + kc + kk);
      bT[kk + 0][m] = w.x; bT[kk + 1][m] = w.y; bT[kk + 2][m] = w.z; bT[kk + 3][m] = w.w;
    }
    __syncthreads();
#pragma unroll 4
    for (int d = 0; d < DCH; ++d) {
      float4 a0 = *reinterpret_cast<const float4*>(&aT[d][ty * 8]);
      float4 a1 = *reinterpret_cast<const float4*>(&aT[d][ty * 8 + 4]);
      float4 b = *reinterpret_cast<const float4*>(&bT[d][tx * 4]);
      float av[8] = {a0.x, a0.y, a0.z, a0.w, a1.x, a1.y, a1.z, a1.w};
      float bv[4] = {b.x, b.y, b.z, b.w};
#pragma unroll
      for (int i = 0; i < 8; ++i)
#pragma unroll
        for (int j = 0; j < 4; ++j) acc[i][j] = fmaf(av[i], bv[j], acc[i][j]);
    }
  }
#pragma unroll
  for (int i = 0; i < 8; ++i) {
    int m = m0 + ty * 8 + i, n = n0 + tx * 4;
    float4 hv;
#pragma unroll
    for (int j = 0; j < 4; ++j) {
#pragma clang fp contract(off)
      float c = s1[i][j] + acc[i][j];
      float pre = c + in_b[n + j];
      ((float*)&hv)[j] = tanhf(pre);
    }
    *reinterpret_cast<float4*>(res + (size_t)m * DC + n) = hv;
  }
}

// ---------------- K2a: per-stage MFMA scoring ----------------
__global__ __launch_bounds__(256, 2) void score_kernel(
    const float* __restrict__ e2,
    const unsigned short* __restrict__ cb_h, const unsigned short* __restrict__ cb_l,
    const float* __restrict__ res, int* __restrict__ win_g, int* __restrict__ flag_g,
    int s) {
  __shared__ __align__(16) unsigned short a_hi[32 * TOK * 8];  // 32KB
  __shared__ __align__(16) unsigned short a_lo[32 * TOK * 8];  // 32KB
  __shared__ float m1s[4 * TOK], m2s[4 * TOK];
  __shared__ int   i1s[4 * TOK];

  const int thr = threadIdx.x;
  const int lane = thr & 63;
  const int w = thr >> 6;        // wave 0..3 -> bins [w*256, w*256+256)
  const int lg = lane >> 4;      // k-subgroup (A/B), row-subgroup (C)
  const int lc = lane & 15;      // A row-in-tile / B,C col(bin)-in-tile
  const int m0 = blockIdx.x * TOK;
  const float* e2s = e2 + (size_t)s * NBINS;
  const unsigned short* bhp = cb_h + (size_t)s * (32 * 1024 * 8);
  const unsigned short* blp = cb_l + (size_t)s * (32 * 1024 * 8);

  // ---- A build: -2*r as bf16 hi/lo into LDS ----
  {
    int row = thr >> 2, d0 = (thr & 3) << 6;
    const float* rrow = res + (size_t)(m0 + row) * DC + d0;
#pragma unroll
    for (int c = 0; c < 8; ++c) {
      float4 r0 = *reinterpret_cast<const float4*>(rrow + c * 8);
      float4 r1 = *reinterpret_cast<const float4*>(rrow + c * 8 + 4);
      float rv[8] = {r0.x, r0.y, r0.z, r0.w, r1.x, r1.y, r1.z, r1.w};
      unsigned short hh[8], ll[8];
#pragma unroll
      for (int j = 0; j < 8; ++j) {
        float xv = -2.0f * rv[j];
        unsigned short h = f2bf(xv);
        hh[j] = h; ll[j] = f2bf(xv - bf2f(h));
      }
      int k8 = (d0 >> 3) + c;
      store8s(a_hi + ((size_t)k8 * TOK + row) * 8, hh);
      store8s(a_lo + ((size_t)k8 * TOK + row) * 8, ll);
    }
  }
  m1s[thr] = 3.4028235e38f; m2s[thr] = 3.4028235e38f; i1s[thr] = 0;
  __syncthreads();

  for (int c = 0; c < 4; ++c) {
    const int bbase = w * 256 + c * 64;
    f32x4 acc[4][4];
#pragma unroll
    for (int nt = 0; nt < 4; ++nt) {
      float ev = e2s[bbase + nt * 16 + lc];
      f32x4 iv = {ev, ev, ev, ev};
#pragma unroll
      for (int rt = 0; rt < 4; ++rt) acc[rt][nt] = iv;
    }
#pragma unroll 2
    for (int kstep = 0; kstep < 8; ++kstep) {
      short8v ah[4], al[4];
#pragma unroll
      for (int rt = 0; rt < 4; ++rt) {
        int off = ((kstep * 4 + lg) * TOK + rt * 16 + lc) * 8;
        ah[rt] = load8s(a_hi + off);
        al[rt] = load8s(a_lo + off);
      }
      short8v bh[4], bl[4];
#pragma unroll
      for (int nt = 0; nt < 4; ++nt) {
        size_t boff = ((size_t)(kstep * 4 + lg) * 1024 + bbase + nt * 16 + lc) * 8;
        bh[nt] = load8s(bhp + boff);
        bl[nt] = load8s(blp + boff);
      }
      __builtin_amdgcn_s_setprio(1);
#pragma unroll
      for (int nt = 0; nt < 4; ++nt)
#pragma unroll
        for (int rt = 0; rt < 4; ++rt)
          acc[rt][nt] = __builtin_amdgcn_mfma_f32_16x16x32_bf16(ah[rt], bh[nt], acc[rt][nt], 0, 0, 0);
#pragma unroll
      for (int nt = 0; nt < 4; ++nt)
#pragma unroll
        for (int rt = 0; rt < 4; ++rt)
          acc[rt][nt] = __builtin_amdgcn_mfma_f32_16x16x32_bf16(ah[rt], bl[nt], acc[rt][nt], 0, 0, 0);
#pragma unroll
      for (int nt = 0; nt < 4; ++nt)
#pragma unroll
        for (int rt = 0; rt < 4; ++rt)
          acc[rt][nt] = __builtin_amdgcn_mfma_f32_16x16x32_bf16(al[rt], bh[nt], acc[rt][nt], 0, 0, 0);
      __builtin_amdgcn_s_setprio(0);
    }
    // fold this chunk into per-wave LDS top-2 (bins ascending)
#pragma unroll
    for (int rt = 0; rt < 4; ++rt)
#pragma unroll
      for (int reg = 0; reg < 4; ++reg) {
        float m1 = 3.4028235e38f, m2 = 3.4028235e38f; int i1 = 0;
#pragma unroll
        for (int nt = 0; nt < 4; ++nt) {
          float v = acc[rt][nt][reg];
          int b = bbase + nt * 16 + lc;
          if (v < m1) { m2 = m1; m1 = v; i1 = b; }
          else m2 = fminf(m2, v);
        }
#pragma unroll
        for (int msk = 1; msk < 16; msk <<= 1) {
          float om1 = __shfl_xor(m1, msk, 64);
          float om2 = __shfl_xor(m2, msk, 64);
          int   oi1 = __shfl_xor(i1, msk, 64);
          if (om1 < m1 || (om1 == m1 && oi1 < i1)) { m2 = fminf(m1, om2); m1 = om1; i1 = oi1; }
          else m2 = fminf(m2, om1);
        }
        if (lc == 0) {
          int sidx = w * TOK + rt * 16 + lg * 4 + reg;
          float pm1 = m1s[sidx], pm2 = m2s[sidx]; int pi1 = i1s[sidx];
          if (m1 < pm1 || (m1 == pm1 && i1 < pi1)) {
            m1s[sidx] = m1; m2s[sidx] = fminf(pm1, m2); i1s[sidx] = i1;
          } else {
            m2s[sidx] = fminf(pm2, m1);
          }
        }
      }
  }
  __syncthreads();
  // final per-row merge across waves -> winner + margin flag -> global
  if (thr < TOK) {
    float m1 = m1s[thr], m2 = m2s[thr]; int i1 = i1s[thr];
#pragma unroll
    for (int ww = 1; ww < 4; ++ww) {
      float om1 = m1s[ww * TOK + thr], om2 = m2s[ww * TOK + thr];
      int oi1 = i1s[ww * TOK + thr];
      if (om1 < m1 || (om1 == m1 && oi1 < i1)) { m2 = fminf(m1, om2); m1 = om1; i1 = oi1; }
      else m2 = fminf(m2, om1);
    }
    win_g[m0 + thr] = i1;
    flag_g[m0 + thr] = (m2 - m1 < MARGIN) ? 1 : 0;
  }
}

// ---------------- K2b: per-stage fix: np re-rank + np residual update ----------------
__global__ __launch_bounds__(256) void fix_kernel(
    const float* __restrict__ cb, const float* __restrict__ e2,
    const int* __restrict__ win_g, const int* __restrict__ flag_g,
    float* __restrict__ res, float* __restrict__ idx_f, double* __restrict__ partial,
    int s) {
  __shared__ int win_l[TOK], flag_l[TOK];
  __shared__ __align__(16) float rrow_s[256];
  __shared__ float redf[4];
  __shared__ int   redi[4];
  __shared__ double wsum[4];
  const int thr = threadIdx.x;
  const int lane = thr & 63;
  const int w = thr >> 6;
  const int m0 = blockIdx.x * TOK;
  const float* cbs = cb + (size_t)s * NBINS * DC;
  const float* e2s = e2 + (size_t)s * NBINS;
  double sqacc = 0.0;

  if (thr < TOK) { win_l[thr] = win_g[m0 + thr]; flag_l[thr] = flag_g[m0 + thr]; }
  __syncthreads();
  // ---- np-bit re-rank for flagged rows (rare; uniform branch) ----
  for (int row = 0; row < TOK; ++row) {
    if (!flag_l[row]) continue;
    if (thr < 64)
      reinterpret_cast<float4*>(rrow_s)[thr] =
          reinterpret_cast<const float4*>(res + (size_t)(m0 + row) * DC)[thr];
    __syncthreads();
    float r2 = np_sumsq256(rrow_s);
    float best = 3.4028235e38f; int bb = 0;
#pragma unroll
    for (int jj = 0; jj < 4; ++jj) {
      int b = thr * 4 + jj;
      const float4* e4 = reinterpret_cast<const float4*>(cbs + (size_t)b * DC);
      const float4* r4 = reinterpret_cast<const float4*>(rrow_s);
      float accv = 0.f;
      for (int q = 0; q < 64; ++q) {   // d ascending: sgemm-chain bits
        float4 ev = e4[q], rv = r4[q];
        accv = fmaf(rv.x, ev.x, accv);
        accv = fmaf(rv.y, ev.y, accv);
        accv = fmaf(rv.z, ev.z, accv);
        accv = fmaf(rv.w, ev.w, accv);
      }
      {
#pragma clang fp contract(off)
        float t = r2 - 2.0f * accv;
        float dist = t + e2s[b];
        if (dist < best) { best = dist; bb = b; }
      }
    }
#pragma unroll
    for (int msk = 1; msk < 64; msk <<= 1) {
      float ov = __shfl_xor(best, msk, 64);
      int   ob = __shfl_xor(bb, msk, 64);
      if (ov < best || (ov == best && ob < bb)) { best = ov; bb = ob; }
    }
    if (lane == 0) { redf[w] = best; redi[w] = bb; }
    __syncthreads();
    if (thr == 0) {
      float bs = redf[0]; int bfin = redi[0];
#pragma unroll
      for (int ww = 1; ww < 4; ++ww)
        if (redf[ww] < bs || (redf[ww] == bs && redi[ww] < bfin)) { bs = redf[ww]; bfin = redi[ww]; }
      win_l[row] = bfin;
    }
    __syncthreads();
  }
  // ---- residual update (np state bits) + commit acc ----
  {
    int row = thr >> 2, d0 = (thr & 3) << 6;
    int wbin = win_l[row];
    const float* erow = cbs + (size_t)wbin * DC + d0;
    float* rrow = res + (size_t)(m0 + row) * DC + d0;
#pragma unroll
    for (int c = 0; c < 8; ++c) {
      float4 r0 = *reinterpret_cast<const float4*>(rrow + c * 8);
      float4 r1 = *reinterpret_cast<const float4*>(rrow + c * 8 + 4);
      float4 e0 = *reinterpret_cast<const float4*>(erow + c * 8);
      float4 e1 = *reinterpret_cast<const float4*>(erow + c * 8 + 4);
      float nv[8] = {r0.x - e0.x, r0.y - e0.y, r0.z - e0.z, r0.w - e0.w,
                     r1.x - e1.x, r1.y - e1.y, r1.z - e1.z, r1.w - e1.w};
#pragma unroll
      for (int j = 0; j < 8; ++j) sqacc += (double)nv[j] * nv[j];
      *reinterpret_cast<float4*>(rrow + c * 8) = (float4){nv[0], nv[1], nv[2], nv[3]};
      *reinterpret_cast<float4*>(rrow + c * 8 + 4) = (float4){nv[4], nv[5], nv[6], nv[7]};
    }
    if (thr < TOK) idx_f[(size_t)s * NTOK + m0 + thr] = (float)win_l[thr];
  }
  // deterministic per-block commit partial (fp64)
#pragma unroll
  for (int msk = 1; msk < 64; msk <<= 1) sqacc += __shfl_xor(sqacc, msk, 64);
  if (lane == 0) wsum[w] = sqacc;
  __syncthreads();
  if (thr == 0) {
    double t = 0.0;
#pragma unroll
    for (int ww = 0; ww < 4; ++ww) t += wsum[ww];
    partial[(size_t)s * STG_BLOCKS + blockIdx.x] = t;
  }
}

// ---------------- K4: finalize commit loss (fixed order, 8*512 partials) ----------------
__global__ void finalize_kernel(const double* __restrict__ partial, float* __restrict__ out_last) {
  __shared__ double acc_s[64];
  int t = threadIdx.x;
  double a = 0.0;
  for (int i = 0; i < 64; ++i) a += partial[(size_t)t * 64 + i];
  acc_s[t] = a;
  __syncthreads();
  if (t == 0) {
    double tot = 0.0;
    for (int i = 0; i < 64; ++i) tot += acc_s[i];
    out_last[0] = (float)(0.1 * tot / 8388608.0);
  }
}

// ---------------- K3: out-projection via 3-pass bf16 hi/lo MFMA ----------------
__global__ __launch_bounds__(256) void out_proj_kernel(
    const float* __restrict__ cb, const float* __restrict__ idx_f,
    const float* __restrict__ out_w, const float* __restrict__ out_b,
    float* __restrict__ out) {
  __shared__ __align__(16) unsigned short a_hi[32 * 32 * 8];  // 16KB
  __shared__ __align__(16) unsigned short a_lo[32 * 32 * 8];  // 16KB
  const int thr = threadIdx.x;
  const int lane = thr & 63;
  const int w = thr >> 6;        // wave 0..3 -> n in [w*128, w*128+128)
  const int lg = lane >> 4;
  const int lc = lane & 15;
  const int m0 = blockIdx.x * 32;

  // ---- gather q = sum_s cb[s][idx_s[m]] (fp32), hi/lo split into LDS ----
  {
    int row = thr >> 3, d0 = (thr & 7) << 5;   // 8 threads/row, 32 d each
    int m = m0 + row;
    int idxs[NQ];
#pragma unroll
    for (int s = 0; s < NQ; ++s) idxs[s] = (int)idx_f[(size_t)s * NTOK + m];
#pragma unroll
    for (int c = 0; c < 4; ++c) {
      int d = d0 + c * 8;
      float q[8] = {0.f, 0.f, 0.f, 0.f, 0.f, 0.f, 0.f, 0.f};
#pragma unroll
      for (int s = 0; s < NQ; ++s) {
        const float4* e4 = reinterpret_cast<const float4*>(
            cb + ((size_t)s * NBINS + idxs[s]) * DC + d);
        float4 e0 = e4[0], e1 = e4[1];
        q[0] += e0.x; q[1] += e0.y; q[2] += e0.z; q[3] += e0.w;
        q[4] += e1.x; q[5] += e1.y; q[6] += e1.z; q[7] += e1.w;
      }
      unsigned short hh[8], ll[8];
#pragma unroll
      for (int j = 0; j < 8; ++j) {
        unsigned short h = f2bf(q[j]);
        hh[j] = h; ll[j] = f2bf(q[j] - bf2f(h));
      }
      int k8 = d >> 3;
      store8s(a_hi + ((size_t)k8 * 32 + row) * 8, hh);
      store8s(a_lo + ((size_t)k8 * 32 + row) * 8, ll);
    }
  }
  __syncthreads();

  // ---- 3-pass hi/lo MFMA: acc starts at out_b ----
  f32x4 acc[2][8];
#pragma unroll
  for (int nt = 0; nt < 8; ++nt) {
    float bv = out_b[w * 128 + nt * 16 + lc];
    f32x4 iv = {bv, bv, bv, bv};
    acc[0][nt] = iv; acc[1][nt] = iv;
  }
#pragma unroll 2
  for (int kstep = 0; kstep < 8; ++kstep) {
    short8v ah[2], al[2];
#pragma unroll
    for (int rt = 0; rt < 2; ++rt) {
      int off = ((kstep * 4 + lg) * 32 + rt * 16 + lc) * 8;
      ah[rt] = load8s(a_hi + off);
      al[rt] = load8s(a_lo + off);
    }
#pragma unroll
    for (int nt = 0; nt < 8; ++nt) {
      int n = w * 128 + nt * 16 + lc;
      const float* wp = out_w + (size_t)n * DC + (kstep * 4 + lg) * 8;
      float4 w0 = *reinterpret_cast<const float4*>(wp);
      float4 w1 = *reinterpret_cast<const float4*>(wp + 4);
      float wv[8] = {w0.x, w0.y, w0.z, w0.w, w1.x, w1.y, w1.z, w1.w};
      unsigned short bhh[8], bll[8];
#pragma unroll
      for (int j = 0; j < 8; ++j) {
        unsigned short h = f2bf(wv[j]);
        bhh[j] = h; bll[j] = f2bf(wv[j] - bf2f(h));
      }
      short8v bh = pack8s(bhh), bl = pack8s(bll);
      acc[0][nt] = __builtin_amdgcn_mfma_f32_16x16x32_bf16(ah[0], bh, acc[0][nt], 0, 0, 0);
      acc[1][nt] = __builtin_amdgcn_mfma_f32_16x16x32_bf16(ah[1], bh, acc[1][nt], 0, 0, 0);
      acc[0][nt] = __builtin_amdgcn_mfma_f32_16x16x32_bf16(ah[0], bl, acc[0][nt], 0, 0, 0);
      acc[1][nt] = __builtin_amdgcn_mfma_f32_16x16x32_bf16(ah[1], bl, acc[1][nt], 0, 0, 0);
      acc[0][nt] = __builtin_amdgcn_mfma_f32_16x16x32_bf16(al[0], bh, acc[0][nt], 0, 0, 0);
      acc[1][nt] = __builtin_amdgcn_mfma_f32_16x16x32_bf16(al[1], bh, acc[1][nt], 0, 0, 0);
    }
  }
  // ---- C write: m = m0 + rt*16 + lg*4 + reg, n = w*128 + nt*16 + lc ----
#pragma unroll
  for (int rt = 0; rt < 2; ++rt)
#pragma unroll
    for (int nt = 0; nt < 8; ++nt) {
      int n = w * 128 + nt * 16 + lc;
#pragma unroll
      for (int reg = 0; reg < 4; ++reg) {
        int m = m0 + rt * 16 + lg * 4 + reg;
        out[(size_t)m * D_IN + n] = acc[rt][nt][reg];
      }
    }
}

extern "C" void kernel_launch(void* const* d_in, const int* in_sizes, int n_in,
                              void* d_out, int out_size, void* d_ws, size_t ws_size,
                              hipStream_t stream) {
  (void)in_sizes; (void)n_in; (void)out_size; (void)d_ws; (void)ws_size;
  const float* x     = (const float*)d_in[0];
  const float* in_w  = (const float*)d_in[1];
  const float* in_b  = (const float*)d_in[2];
  const float* out_w = (const float*)d_in[3];
  const float* out_b = (const float*)d_in[4];
  const float* cb    = (const float*)d_in[5];
  float* out = (float*)d_out;
  // d_out scratch layout (consumed before out_proj overwrites [0,16.7M)):
  float* res    = out;                                  // 8,388,608 f32 residual
  float* e2     = out + 8388608;                        // 8192 f32 (np bits)
  double* part  = (double*)(out + 8404992);             // 4096 f64
  unsigned short* cb_h = (unsigned short*)(out + 9000000);   // 2,097,152 bf16
  unsigned short* cb_l = (unsigned short*)(out + 10500000);  // 2,097,152 bf16
  int* win_g   = (int*)(out + 11600000);                // 32768 int
  int* flag_g  = (int*)(out + 11700000);                // 32768 int
  float* idx_f  = out + 16777216;                       // 262,144 f32
  float* c_out  = out + 17039360;                       // 1 f32

  hipLaunchKernelGGL(e2_np_kernel, dim3(32), dim3(256), 0, stream, cb, e2);
  hipLaunchKernelGGL(presplit_kernel, dim3(1024), dim3(256), 0, stream, cb, cb_h, cb_l);
  hipLaunchKernelGGL(in_proj_kernel, dim3(256, 4), dim3(256), 0, stream, x, in_w, in_b, res);
  for (int s = 0; s < NQ; ++s) {
    hipLaunchKernelGGL(score_kernel, dim3(STG_BLOCKS), dim3(256), 0, stream,
                       e2, cb_h, cb_l, res, win_g, flag_g, s);
    hipLaunchKernelGGL(fix_kernel, dim3(STG_BLOCKS), dim3(256), 0, stream,
                       cb, e2, win_g, flag_g, res, idx_f, part, s);
  }
  hipLaunchKernelGGL(finalize_kernel, dim3(1), dim3(64), 0, stream, part, c_out);
  hipLaunchKernelGGL(out_proj_kernel, dim3(1024), dim3(256), 0, stream, cb, idx_f, out_w, out_b, out);
}